// Round 4
// baseline (385.919 us; speedup 1.0000x reference)
//
#include <hip/hip_runtime.h>
#include <math.h>
#include <stdint.h>

#define NHEADS 16
#define DK 128
#define TSEQ 2048
#define DMODEL 2048

typedef __attribute__((ext_vector_type(8))) short short8;
typedef __attribute__((ext_vector_type(4))) float floatx4;

__device__ __forceinline__ float bf2f(unsigned short h) {
    return __uint_as_float(((unsigned int)h) << 16);
}
__device__ __forceinline__ unsigned short f2bf(float f) {
    unsigned int u = __float_as_uint(f);
    u += 0x7FFFu + ((u >> 16) & 1u);
    return (unsigned short)(u >> 16);
}
__device__ __forceinline__ void async16(unsigned short* lds, const unsigned short* g) {
    __builtin_amdgcn_global_load_lds(
        (const __attribute__((address_space(1))) uint32_t*)g,
        (__attribute__((address_space(3))) uint32_t*)lds, 16, 0, 0);
}

// ===================== cast f32 -> bf16, 8 elems/thread =====================
__global__ __launch_bounds__(256) void cast_f32_to_bf16(
    const float* __restrict__ in, unsigned short* __restrict__ out, int n8)
{
    const int i = blockIdx.x * 256 + threadIdx.x;
    if (i >= n8) return;
    const float4* p4 = reinterpret_cast<const float4*>(in) + 2 * (size_t)i;
    const float4 a = p4[0], b = p4[1];
    uint32_t w0 = (uint32_t)f2bf(a.x) | ((uint32_t)f2bf(a.y) << 16);
    uint32_t w1 = (uint32_t)f2bf(a.z) | ((uint32_t)f2bf(a.w) << 16);
    uint32_t w2 = (uint32_t)f2bf(b.x) | ((uint32_t)f2bf(b.y) << 16);
    uint32_t w3 = (uint32_t)f2bf(b.z) | ((uint32_t)f2bf(b.w) << 16);
    uint4 o; o.x = w0; o.y = w1; o.z = w2; o.w = w3;
    *reinterpret_cast<uint4*>(out + 8 * (size_t)i) = o;
}

// ===================== 8-phase 256x256 bf16 GEMM (C = A @ B^T), bf16 out =====================
// T3+T4 (counted vmcnt, raw barriers) + T2 (chunk-XOR swizzle both sides) + T5 (setprio)
// + T1 (XCD swizzle). 512 thr = 8 waves (2M x 4N); per-wave 128x64 out; BK=64; LDS 128KB dbuf.
__global__ __launch_bounds__(512, 1) void gemm_bt_bf16_8ph(
    const unsigned short* __restrict__ A, const unsigned short* __restrict__ B,
    unsigned short* __restrict__ C, int M, int N, int K, int gx)
{
    __shared__ unsigned short As[2][256 * 64];
    __shared__ unsigned short Bs[2][256 * 64];

    const int t = threadIdx.x;
    const int lane = t & 63, w = t >> 6;
    const int wr = w >> 2, wc = w & 3;
    const int lr = lane & 15, hi = lane >> 4;

    // XCD-aware bijective block swizzle (grid % 8 == 0 guaranteed by launch)
    const int nwg = (int)gridDim.x;
    const int cpx = nwg >> 3;
    const int swz = ((nwg & 7) == 0) ? ((int)(blockIdx.x & 7) * cpx + (int)(blockIdx.x >> 3))
                                     : (int)blockIdx.x;
    const int row0 = (swz / gx) * 256;
    const int col0 = (swz % gx) * 256;

    // staging geometry: half-tile = 128 rows x 64 cols bf16 = 1024 chunks of 16B;
    // thread covers chunks s0, s1. LDS dest linear; SOURCE pre-swizzled (chunk ^= row&7).
    const int s0 = t, s1 = t + 512;
    const int r0 = s0 >> 3, c0 = (s0 & 7) ^ (r0 & 7);
    const int r1 = s1 >> 3, c1 = (s1 & 7) ^ (r1 & 7);
    const unsigned short* a0 = A + (size_t)(row0 + r0) * K + c0 * 8;
    const unsigned short* a1 = A + (size_t)(row0 + r1) * K + c1 * 8;
    const unsigned short* b0 = B + (size_t)(col0 + r0) * K + c0 * 8;
    const unsigned short* b1 = B + (size_t)(col0 + r1) * K + c1 * 8;
    const size_t hstep = (size_t)128 * K;

    floatx4 acc[8][4];
#pragma unroll
    for (int m = 0; m < 8; m++)
#pragma unroll
        for (int n = 0; n < 4; n++)
#pragma unroll
            for (int e = 0; e < 4; e++) acc[m][n][e] = 0.f;

    // ds_read chunk index per lane: (kk*4 + hi) ^ (lr&7)  [row&7 == lr&7 for all frag rows]
    const int ch0 = (0 * 4 + hi) ^ (lr & 7);
    const int ch1 = (1 * 4 + hi) ^ (lr & 7);

#define STAGE(nb, k0n) do { \
        async16(&As[nb][s0 * 8],        a0 + (k0n)); \
        async16(&As[nb][8192 + s0 * 8], a0 + hstep + (k0n)); \
        async16(&As[nb][s1 * 8],        a1 + (k0n)); \
        async16(&As[nb][8192 + s1 * 8], a1 + hstep + (k0n)); \
        async16(&Bs[nb][s0 * 8],        b0 + (k0n)); \
        async16(&Bs[nb][8192 + s0 * 8], b0 + hstep + (k0n)); \
        async16(&Bs[nb][s1 * 8],        b1 + (k0n)); \
        async16(&Bs[nb][8192 + s1 * 8], b1 + hstep + (k0n)); \
    } while (0)

    STAGE(0, 0);
    const int NT = K >> 6;

    short8 av[4][2], bv[2][2];

    for (int kt = 0; kt < NT; ++kt) {
        const int cur = kt & 1;
        const unsigned short* __restrict__ Ac = &As[cur][0];
        const unsigned short* __restrict__ Bc = &Bs[cur][0];

        // ---- phase 0: prefetch next tile, counted wait, quadrant (mh0, nh0) ----
        if (kt + 1 < NT) {
            STAGE(cur ^ 1, (kt + 1) << 6);
            asm volatile("s_waitcnt vmcnt(8)" ::: "memory");
        } else {
            asm volatile("s_waitcnt vmcnt(0)" ::: "memory");
        }
        __builtin_amdgcn_s_barrier();   // all waves' tile-kt staging landed
        __builtin_amdgcn_sched_barrier(0);

#pragma unroll
        for (int m = 0; m < 4; m++) {
            const int ar = (wr * 128 + m * 16 + lr) * 64;
            av[m][0] = *(const short8*)&Ac[ar + ch0 * 8];
            av[m][1] = *(const short8*)&Ac[ar + ch1 * 8];
        }
#pragma unroll
        for (int n = 0; n < 2; n++) {
            const int br = (wc * 64 + n * 16 + lr) * 64;
            bv[n][0] = *(const short8*)&Bc[br + ch0 * 8];
            bv[n][1] = *(const short8*)&Bc[br + ch1 * 8];
        }
        asm volatile("s_waitcnt lgkmcnt(0)" ::: "memory");
        __builtin_amdgcn_sched_barrier(0);
        __builtin_amdgcn_s_setprio(1);
#pragma unroll
        for (int m = 0; m < 4; m++)
#pragma unroll
            for (int n = 0; n < 2; n++) {
                acc[m][n] = __builtin_amdgcn_mfma_f32_16x16x32_bf16(av[m][0], bv[n][0], acc[m][n], 0, 0, 0);
                acc[m][n] = __builtin_amdgcn_mfma_f32_16x16x32_bf16(av[m][1], bv[n][1], acc[m][n], 0, 0, 0);
            }
        __builtin_amdgcn_s_setprio(0);
        __builtin_amdgcn_s_barrier();

        // ---- phase 1: quadrant (mh0, nh1) — reuse av ----
#pragma unroll
        for (int n = 0; n < 2; n++) {
            const int br = (wc * 64 + (2 + n) * 16 + lr) * 64;
            bv[n][0] = *(const short8*)&Bc[br + ch0 * 8];
            bv[n][1] = *(const short8*)&Bc[br + ch1 * 8];
        }
        __builtin_amdgcn_s_barrier();
        asm volatile("s_waitcnt lgkmcnt(0)" ::: "memory");
        __builtin_amdgcn_sched_barrier(0);
        __builtin_amdgcn_s_setprio(1);
#pragma unroll
        for (int m = 0; m < 4; m++)
#pragma unroll
            for (int n = 0; n < 2; n++) {
                acc[m][2 + n] = __builtin_amdgcn_mfma_f32_16x16x32_bf16(av[m][0], bv[n][0], acc[m][2 + n], 0, 0, 0);
                acc[m][2 + n] = __builtin_amdgcn_mfma_f32_16x16x32_bf16(av[m][1], bv[n][1], acc[m][2 + n], 0, 0, 0);
            }
        __builtin_amdgcn_s_setprio(0);
        __builtin_amdgcn_s_barrier();

        // ---- phase 2: quadrant (mh1, nh0) ----
#pragma unroll
        for (int m = 0; m < 4; m++) {
            const int ar = (wr * 128 + (4 + m) * 16 + lr) * 64;
            av[m][0] = *(const short8*)&Ac[ar + ch0 * 8];
            av[m][1] = *(const short8*)&Ac[ar + ch1 * 8];
        }
#pragma unroll
        for (int n = 0; n < 2; n++) {
            const int br = (wc * 64 + n * 16 + lr) * 64;
            bv[n][0] = *(const short8*)&Bc[br + ch0 * 8];
            bv[n][1] = *(const short8*)&Bc[br + ch1 * 8];
        }
        __builtin_amdgcn_s_barrier();
        asm volatile("s_waitcnt lgkmcnt(0)" ::: "memory");
        __builtin_amdgcn_sched_barrier(0);
        __builtin_amdgcn_s_setprio(1);
#pragma unroll
        for (int m = 0; m < 4; m++)
#pragma unroll
            for (int n = 0; n < 2; n++) {
                acc[4 + m][n] = __builtin_amdgcn_mfma_f32_16x16x32_bf16(av[m][0], bv[n][0], acc[4 + m][n], 0, 0, 0);
                acc[4 + m][n] = __builtin_amdgcn_mfma_f32_16x16x32_bf16(av[m][1], bv[n][1], acc[4 + m][n], 0, 0, 0);
            }
        __builtin_amdgcn_s_setprio(0);
        __builtin_amdgcn_s_barrier();

        // ---- phase 3: quadrant (mh1, nh1) — reuse av ----
#pragma unroll
        for (int n = 0; n < 2; n++) {
            const int br = (wc * 64 + (2 + n) * 16 + lr) * 64;
            bv[n][0] = *(const short8*)&Bc[br + ch0 * 8];
            bv[n][1] = *(const short8*)&Bc[br + ch1 * 8];
        }
        __builtin_amdgcn_s_barrier();
        asm volatile("s_waitcnt lgkmcnt(0)" ::: "memory");
        __builtin_amdgcn_sched_barrier(0);
        __builtin_amdgcn_s_setprio(1);
#pragma unroll
        for (int m = 0; m < 4; m++)
#pragma unroll
            for (int n = 0; n < 2; n++) {
                acc[4 + m][2 + n] = __builtin_amdgcn_mfma_f32_16x16x32_bf16(av[m][0], bv[n][0], acc[4 + m][2 + n], 0, 0, 0);
                acc[4 + m][2 + n] = __builtin_amdgcn_mfma_f32_16x16x32_bf16(av[m][1], bv[n][1], acc[4 + m][2 + n], 0, 0, 0);
            }
        __builtin_amdgcn_s_setprio(0);
        __builtin_amdgcn_s_barrier();   // all reads of buf[cur] done -> next tile may overwrite
    }
#undef STAGE

    // ---- epilogue: D layout col=lr, row=hi*4+j ----
#pragma unroll
    for (int m = 0; m < 8; m++)
#pragma unroll
        for (int n = 0; n < 4; n++) {
            const int col = col0 + wc * 64 + n * 16 + lr;
#pragma unroll
            for (int j = 0; j < 4; j++) {
                const int row = row0 + wr * 128 + m * 16 + hi * 4 + j;
                C[(size_t)row * N + col] = f2bf(acc[m][n][j]);
            }
        }
}

// ===================== m97-style bf16 GEMM (kept for the 2048-wide output proj) =====================
template<int OUT_BF16>
__global__ __launch_bounds__(256) void gemm_bt_bf16(
    const unsigned short* __restrict__ A, const unsigned short* __restrict__ B,
    void* __restrict__ Cv, int M, int N, int K)
{
    __shared__ unsigned short As[128 * 32];
    __shared__ unsigned short Bs[128 * 32];

    const int t = threadIdx.x;
    const int lane = t & 63, w = t >> 6;
    const int row0 = blockIdx.y * 128, col0 = blockIdx.x * 128;
    const int wr = (w >> 1) * 64, wc = (w & 1) * 64;
    const int lr = lane & 15, lk = lane >> 4;

    floatx4 acc[4][4];
#pragma unroll
    for (int i = 0; i < 4; i++)
#pragma unroll
        for (int j = 0; j < 4; j++)
#pragma unroll
            for (int e = 0; e < 4; e++) acc[i][j][e] = 0.f;

    const int c0 = w * 64 + lane, c1 = c0 + 256;
    const size_t ga0 = (size_t)(row0 + (c0 >> 2)) * K + ((c0 & 3) << 3);
    const size_t ga1 = (size_t)(row0 + (c1 >> 2)) * K + ((c1 & 3) << 3);
    const size_t gb0 = (size_t)(col0 + (c0 >> 2)) * K + ((c0 & 3) << 3);
    const size_t gb1 = (size_t)(col0 + (c1 >> 2)) * K + ((c1 & 3) << 3);

    for (int k0 = 0; k0 < K; k0 += 32) {
        async16(&As[c0 * 8], A + ga0 + k0);
        async16(&As[c1 * 8], A + ga1 + k0);
        async16(&Bs[c0 * 8], B + gb0 + k0);
        async16(&Bs[c1 * 8], B + gb1 + k0);
        __syncthreads();

        short8 a[4], b[4];
#pragma unroll
        for (int mi = 0; mi < 4; mi++)
            a[mi] = *(const short8*)&As[(wr + mi * 16 + lr) * 32 + lk * 8];
#pragma unroll
        for (int ni = 0; ni < 4; ni++)
            b[ni] = *(const short8*)&Bs[(wc + ni * 16 + lr) * 32 + lk * 8];
#pragma unroll
        for (int mi = 0; mi < 4; mi++)
#pragma unroll
            for (int ni = 0; ni < 4; ni++)
                acc[mi][ni] = __builtin_amdgcn_mfma_f32_16x16x32_bf16(
                    a[mi], b[ni], acc[mi][ni], 0, 0, 0);
        __syncthreads();
    }

#pragma unroll
    for (int mi = 0; mi < 4; mi++)
#pragma unroll
        for (int ni = 0; ni < 4; ni++) {
            const int colb = col0 + wc + ni * 16 + lr;
#pragma unroll
            for (int j = 0; j < 4; j++) {
                const int rowb = row0 + wr + mi * 16 + lk * 4 + j;
                if (OUT_BF16)
                    ((unsigned short*)Cv)[(size_t)rowb * N + colb] = f2bf(acc[mi][ni][j]);
                else
                    ((float*)Cv)[(size_t)rowb * N + colb] = acc[mi][ni][j];
            }
        }
}

// ===================== RoPE table + apply =====================
__global__ __launch_bounds__(256) void rope_table_kernel(
    const int* __restrict__ pos, float2* __restrict__ tab)
{
    const int idx = blockIdx.x * 256 + threadIdx.x;   // 2048*64
    const int tt = idx >> 6, i = idx & 63;
    const double inv_freq = exp(-log(10000.0) * (double)i / 64.0);
    const double ang = (double)pos[tt] * inv_freq;
    tab[idx] = make_float2((float)cos(ang), (float)sin(ang));
}

__global__ __launch_bounds__(256) void rope_apply_kernel(
    unsigned short* __restrict__ qkv, const float2* __restrict__ tab)
{
    const int idx = blockIdx.x * 256 + threadIdx.x;   // B*T*2*16*64 = 8388608
    const int i  = idx & 63;
    const int h  = (idx >> 6) & 15;
    const int qk = (idx >> 10) & 1;
    const int tt = (idx >> 11) & (TSEQ - 1);
    const int b  = idx >> 22;
    const float2 cs = tab[(tt << 6) | i];
    const size_t base = (size_t)(b * TSEQ + tt) * (3 * DMODEL) + qk * DMODEL + h * DK + 2 * i;
    const uint32_t pv = *(const uint32_t*)&qkv[base];
    const float e = bf2f((unsigned short)(pv & 0xFFFF));
    const float o = bf2f((unsigned short)(pv >> 16));
    const uint32_t rv = (uint32_t)f2bf(e * cs.x - o * cs.y) |
                        ((uint32_t)f2bf(e * cs.y + o * cs.x) << 16);
    *(uint32_t*)&qkv[base] = rv;
}

// ===================== V transpose: qkvb v-part -> vt[bh][d][t] =====================
__global__ __launch_bounds__(256) void transpose_v_kernel(
    const unsigned short* __restrict__ qkvb, unsigned short* __restrict__ vt)
{
    __shared__ unsigned short tile[32][33];
    const int bh = blockIdx.z, b = bh >> 4, h = bh & 15;
    const int t0 = blockIdx.x * 32, d0 = blockIdx.y * 32;
    const int tx = threadIdx.x & 31, ty = threadIdx.x >> 5;
#pragma unroll
    for (int k = 0; k < 32; k += 8) {
        const int tt = t0 + ty + k;
        tile[ty + k][tx] = qkvb[(size_t)(b * TSEQ + tt) * (3 * DMODEL) + 2 * DMODEL + h * DK + d0 + tx];
    }
    __syncthreads();
#pragma unroll
    for (int k = 0; k < 32; k += 8) {
        const int d = d0 + ty + k;
        vt[(size_t)(bh * DK + d) * TSEQ + t0 + tx] = tile[tx][ty + k];
    }
}

// ===================== MFMA flash attention v3 (unchanged from round 3) =====================
__global__ __launch_bounds__(256, 2) void attn_mfma2_kernel(
    const unsigned short* __restrict__ qkvb, const unsigned short* __restrict__ vt,
    unsigned short* __restrict__ outb)
{
    __shared__ unsigned short Ks[2][64 * 128];
    __shared__ unsigned short Vs[128 * 64];
    __shared__ unsigned short Ps[4][32 * 64];

    const int t = threadIdx.x;
    const int lane = t & 63, w = t >> 6;
    const int lr = lane & 15, hi = lane >> 4;
    const int bh = blockIdx.y, b = bh >> 4, h = bh & 15;
    const int qc = (int)gridDim.x - 1 - (int)blockIdx.x;
    const int q0 = qc * 128;
    const int q0w = q0 + w * 32;
    const float scale = 0.08838834764831845f;
    const size_t QROW = 3 * DMODEL;

    const unsigned short* kg = qkvb + (size_t)b * TSEQ * QROW + DMODEL + h * DK;
    const unsigned short* vg = vt + (size_t)bh * DK * TSEQ;

    short8 qf[2][4];
    {
        const unsigned short* qbase = qkvb + (size_t)(b * TSEQ + q0w) * QROW + h * DK;
#pragma unroll
        for (int nt = 0; nt < 2; nt++)
#pragma unroll
            for (int ks = 0; ks < 4; ks++) {
                short8 raw = *(const short8*)(qbase + (size_t)(nt * 16 + lr) * QROW + ks * 32 + hi * 8);
                short8 sc;
#pragma unroll
                for (int e = 0; e < 8; e++)
                    sc[e] = (short)f2bf(bf2f((unsigned short)raw[e]) * scale);
                qf[nt][ks] = sc;
            }
    }

    auto stageK = [&](int bufi, int kv0s) {
#pragma unroll
        for (int i = 0; i < 4; i++) {
            const int s = i * 256 + t;
            const int r = s >> 4;
            const int cc = (s & 15) ^ (r & 7);
            async16(&Ks[bufi][s * 8], kg + (size_t)(kv0s + r) * QROW + cc * 8);
        }
    };
    auto stageV = [&](int kv0s) {
#pragma unroll
        for (int i = 0; i < 4; i++) {
            const int s = i * 256 + t;
            const int r = s >> 3;
            const int cc = (s & 7) ^ (r & 7);
            async16(&Vs[s * 8], vg + (size_t)r * TSEQ + kv0s + cc * 8);
        }
    };

    floatx4 accO[2][8];
#pragma unroll
    for (int nt = 0; nt < 2; nt++)
#pragma unroll
        for (int dt = 0; dt < 8; dt++)
#pragma unroll
            for (int e = 0; e < 4; e++) accO[nt][dt][e] = 0.f;
    float mrun[2] = {-1e30f, -1e30f};
    float lrun[2] = {0.f, 0.f};

    const int ntiles = (q0 + 128) / 64;
    int kbuf = 0;

    stageK(0, 0);
    __syncthreads();

    for (int ti = 0; ti < ntiles; ti++) {
        const int kv0 = ti * 64;
        stageV(kv0);
        if (ti + 1 < ntiles) stageK(kbuf ^ 1, kv0 + 64);

        const bool active = (kv0 <= q0w + 31);
        float al[2] = {1.f, 1.f};

        if (active) {
            floatx4 st[4][2];
#pragma unroll
            for (int mt = 0; mt < 4; mt++)
#pragma unroll
                for (int nt = 0; nt < 2; nt++)
#pragma unroll
                    for (int e = 0; e < 4; e++) st[mt][nt][e] = 0.f;
#pragma unroll
            for (int mt = 0; mt < 4; mt++) {
                const int r = mt * 16 + lr;
#pragma unroll
                for (int ks = 0; ks < 4; ks++) {
                    const int ch = (ks * 4 + hi) ^ (r & 7);
                    const short8 kf = *(const short8*)&Ks[kbuf][(r * 16 + ch) * 8];
                    st[mt][0] = __builtin_amdgcn_mfma_f32_16x16x32_bf16(kf, qf[0][ks], st[mt][0], 0, 0, 0);
                    st[mt][1] = __builtin_amdgcn_mfma_f32_16x16x32_bf16(kf, qf[1][ks], st[mt][1], 0, 0, 0);
                }
            }
            if (kv0 + 63 > q0w) {
#pragma unroll
                for (int nt = 0; nt < 2; nt++) {
                    const int qg = q0w + nt * 16 + lr;
#pragma unroll
                    for (int mt = 0; mt < 4; mt++)
#pragma unroll
                        for (int rg = 0; rg < 4; rg++) {
                            const int kvg = kv0 + mt * 16 + hi * 4 + rg;
                            if (kvg > qg) st[mt][nt][rg] = -1e30f;
                        }
                }
            }
            float pm[2];
#pragma unroll
            for (int nt = 0; nt < 2; nt++) {
                float m = -1e30f;
#pragma unroll
                for (int mt = 0; mt < 4; mt++)
#pragma unroll
                    for (int rg = 0; rg < 4; rg++) m = fmaxf(m, st[mt][nt][rg]);
                m = fmaxf(m, __shfl_xor(m, 16, 64));
                m = fmaxf(m, __shfl_xor(m, 32, 64));
                pm[nt] = m;
            }
            if (__any((pm[0] > mrun[0] + 8.f) || (pm[1] > mrun[1] + 8.f))) {
#pragma unroll
                for (int nt = 0; nt < 2; nt++) {
                    const float mn = fmaxf(mrun[nt], pm[nt]);
                    al[nt] = __expf(mrun[nt] - mn);
                    mrun[nt] = mn;
                }
#pragma unroll
                for (int rg = 0; rg < 4; rg++) {
                    const float a0 = __shfl(al[0], hi * 4 + rg, 64);
                    const float a1 = __shfl(al[1], hi * 4 + rg, 64);
#pragma unroll
                    for (int dt = 0; dt < 8; dt++) {
                        accO[0][dt][rg] *= a0;
                        accO[1][dt][rg] *= a1;
                    }
                }
            }
#pragma unroll
            for (int nt = 0; nt < 2; nt++) {
                float ls = 0.f;
#pragma unroll
                for (int mt = 0; mt < 4; mt++)
#pragma unroll
                    for (int rg = 0; rg < 4; rg++) {
                        const float p = __expf(st[mt][nt][rg] - mrun[nt]);
                        ls += p;
                        Ps[w][(nt * 16 + lr) * 64 + mt * 16 + hi * 4 + rg] = f2bf(p);
                    }
                ls += __shfl_xor(ls, 16, 64);
                ls += __shfl_xor(ls, 32, 64);
                lrun[nt] = lrun[nt] * al[nt] + ls;
            }
        }
        __syncthreads();

        if (active) {
#pragma unroll
            for (int ks2 = 0; ks2 < 2; ks2++) {
                const short8 pa0 = *(const short8*)&Ps[w][(0 * 16 + lr) * 64 + ks2 * 32 + hi * 8];
                const short8 pa1 = *(const short8*)&Ps[w][(1 * 16 + lr) * 64 + ks2 * 32 + hi * 8];
#pragma unroll
                for (int dt = 0; dt < 8; dt++) {
                    const int r = dt * 16 + lr;
                    const int ch = (ks2 * 4 + hi) ^ (r & 7);
                    const short8 vf = *(const short8*)&Vs[(r * 8 + ch) * 8];
                    accO[0][dt] = __builtin_amdgcn_mfma_f32_16x16x32_bf16(pa0, vf, accO[0][dt], 0, 0, 0);
                    accO[1][dt] = __builtin_amdgcn_mfma_f32_16x16x32_bf16(pa1, vf, accO[1][dt], 0, 0, 0);
                }
            }
        }
        __syncthreads();
        kbuf ^= 1;
    }

#pragma unroll
    for (int nt = 0; nt < 2; nt++) {
        const float lv_own = 1.f / lrun[nt];
#pragma unroll
        for (int rg = 0; rg < 4; rg++) {
            const float lv = __shfl(lv_own, hi * 4 + rg, 64);
            unsigned short* orow = outb + (size_t)(b * TSEQ + q0w + nt * 16 + hi * 4 + rg) * DMODEL + h * DK;
#pragma unroll
            for (int dt = 0; dt < 8; dt++)
                orow[dt * 16 + lr] = f2bf(accO[nt][dt][rg] * lv);
        }
    }
}

// ===================== launch =====================
extern "C" void kernel_launch(void* const* d_in, const int* in_sizes, int n_in,
                              void* d_out, int out_size, void* d_ws, size_t ws_size,
                              hipStream_t stream)
{
    const float* x    = (const float*)d_in[0];
    const int*   pos  = (const int*)d_in[1];
    const float* Wqkv = (const float*)d_in[2];
    const float* Wo   = (const float*)d_in[3];
    float* out = (float*)d_out;

    unsigned short* qkvb  = (unsigned short*)d_ws;
    unsigned short* vtb   = qkvb + (size_t)25165824;
    unsigned short* xb    = vtb + (size_t)8388608;
    unsigned short* attnb = xb;                         // alias: xb dead after GEMM1
    unsigned short* wqkvb = xb + (size_t)8388608;
    unsigned short* wob   = wqkvb + (size_t)12582912;
    float2* tab = (float2*)(wob + (size_t)4194304);

    const int M = 2 * TSEQ;   // 4096

    cast_f32_to_bf16<<<4096, 256, 0, stream>>>(x, xb, 1048576);
    cast_f32_to_bf16<<<6144, 256, 0, stream>>>(Wqkv, wqkvb, 1572864);
    cast_f32_to_bf16<<<2048, 256, 0, stream>>>(Wo, wob, 524288);
    rope_table_kernel<<<512, 256, 0, stream>>>(pos, tab);

    // qkvb = xb @ wqkvb^T  (4096 x 6144 x 2048), 8-phase 256^2: grid 16x24 = 384 (384%8==0)
    gemm_bt_bf16_8ph<<<dim3(384), 512, 0, stream>>>(xb, wqkvb, qkvb, M, 3 * DMODEL, DMODEL, 24);

    rope_apply_kernel<<<32768, 256, 0, stream>>>(qkvb, tab);
    transpose_v_kernel<<<dim3(64, 4, 32), 256, 0, stream>>>(qkvb, vtb);

    attn_mfma2_kernel<<<dim3(16, 32), 256, 0, stream>>>(qkvb, vtb, attnb);

    gemm_bt_bf16<0><<<dim3(16, 32), 256, 0, stream>>>(attnb, wob, (void*)out, M, DMODEL, DMODEL);
}

// Round 5
// 319.257 us; speedup vs baseline: 1.2088x; 1.2088x over previous
//
#include <hip/hip_runtime.h>
#include <math.h>
#include <stdint.h>

#define NHEADS 16
#define DK 128
#define TSEQ 2048
#define DMODEL 2048

typedef __attribute__((ext_vector_type(8))) short short8;
typedef __attribute__((ext_vector_type(4))) float floatx4;

__device__ __forceinline__ float bf2f(unsigned short h) {
    return __uint_as_float(((unsigned int)h) << 16);
}
__device__ __forceinline__ unsigned short f2bf(float f) {
    unsigned int u = __float_as_uint(f);
    u += 0x7FFFu + ((u >> 16) & 1u);
    return (unsigned short)(u >> 16);
}
__device__ __forceinline__ void async16(unsigned short* lds, const unsigned short* g) {
    __builtin_amdgcn_global_load_lds(
        (const __attribute__((address_space(1))) uint32_t*)g,
        (__attribute__((address_space(3))) uint32_t*)lds, 16, 0, 0);
}

// ===================== cast f32 -> bf16, 8 elems/thread =====================
__global__ __launch_bounds__(256) void cast_f32_to_bf16(
    const float* __restrict__ in, unsigned short* __restrict__ out, int n8)
{
    const int i = blockIdx.x * 256 + threadIdx.x;
    if (i >= n8) return;
    const float4* p4 = reinterpret_cast<const float4*>(in) + 2 * (size_t)i;
    const float4 a = p4[0], b = p4[1];
    uint32_t w0 = (uint32_t)f2bf(a.x) | ((uint32_t)f2bf(a.y) << 16);
    uint32_t w1 = (uint32_t)f2bf(a.z) | ((uint32_t)f2bf(a.w) << 16);
    uint32_t w2 = (uint32_t)f2bf(b.x) | ((uint32_t)f2bf(b.y) << 16);
    uint32_t w3 = (uint32_t)f2bf(b.z) | ((uint32_t)f2bf(b.w) << 16);
    uint4 o; o.x = w0; o.y = w1; o.z = w2; o.w = w3;
    *reinterpret_cast<uint4*>(out + 8 * (size_t)i) = o;
}

// ===================== RoPE table =====================
__global__ __launch_bounds__(256) void rope_table_kernel(
    const int* __restrict__ pos, float2* __restrict__ tab)
{
    const int idx = blockIdx.x * 256 + threadIdx.x;   // 2048*64
    const int tt = idx >> 6, i = idx & 63;
    const double inv_freq = exp(-log(10000.0) * (double)i / 64.0);
    const double ang = (double)pos[tt] * inv_freq;
    tab[idx] = make_float2((float)cos(ang), (float)sin(ang));
}

// ===================== fused QKV GEMM (m97 structure) =====================
// C = x @ Wqkv^T (4096 x 6144 x 2048). Epilogue:
//   cols [0,4096): RoPE in f32 (pair exchange via shfl_xor(1)) -> qkvb (bf16)
//   cols [4096,6144): transposed packed write -> vt[bh][d][token] (bf16)
__global__ __launch_bounds__(256) void gemm_qkv_fused(
    const unsigned short* __restrict__ A, const unsigned short* __restrict__ B,
    unsigned short* __restrict__ qkvb, unsigned short* __restrict__ vt,
    const float2* __restrict__ tab)
{
    const int K = DMODEL, N = 3 * DMODEL;
    __shared__ unsigned short As[128 * 32];
    __shared__ unsigned short Bs[128 * 32];

    const int t = threadIdx.x;
    const int lane = t & 63, w = t >> 6;
    const int row0 = blockIdx.y * 128, col0 = blockIdx.x * 128;
    const int wr = (w >> 1) * 64, wc = (w & 1) * 64;
    const int lr = lane & 15, lk = lane >> 4;

    floatx4 acc[4][4];
#pragma unroll
    for (int i = 0; i < 4; i++)
#pragma unroll
        for (int j = 0; j < 4; j++)
#pragma unroll
            for (int e = 0; e < 4; e++) acc[i][j][e] = 0.f;

    const int c0 = w * 64 + lane, c1 = c0 + 256;
    const size_t ga0 = (size_t)(row0 + (c0 >> 2)) * K + ((c0 & 3) << 3);
    const size_t ga1 = (size_t)(row0 + (c1 >> 2)) * K + ((c1 & 3) << 3);
    const size_t gb0 = (size_t)(col0 + (c0 >> 2)) * K + ((c0 & 3) << 3);
    const size_t gb1 = (size_t)(col0 + (c1 >> 2)) * K + ((c1 & 3) << 3);

    for (int k0 = 0; k0 < K; k0 += 32) {
        async16(&As[c0 * 8], A + ga0 + k0);
        async16(&As[c1 * 8], A + ga1 + k0);
        async16(&Bs[c0 * 8], B + gb0 + k0);
        async16(&Bs[c1 * 8], B + gb1 + k0);
        __syncthreads();

        short8 a[4], b[4];
#pragma unroll
        for (int mi = 0; mi < 4; mi++)
            a[mi] = *(const short8*)&As[(wr + mi * 16 + lr) * 32 + lk * 8];
#pragma unroll
        for (int ni = 0; ni < 4; ni++)
            b[ni] = *(const short8*)&Bs[(wc + ni * 16 + lr) * 32 + lk * 8];
#pragma unroll
        for (int mi = 0; mi < 4; mi++)
#pragma unroll
            for (int ni = 0; ni < 4; ni++)
                acc[mi][ni] = __builtin_amdgcn_mfma_f32_16x16x32_bf16(
                    a[mi], b[ni], acc[mi][ni], 0, 0, 0);
        __syncthreads();
    }

    // ---- fused epilogue (D layout: col = lr, row = lk*4 + j) ----
    if (col0 < 2 * DMODEL) {
        // q or k section: RoPE then store to qkvb
        const int par = lr & 1;
#pragma unroll
        for (int mi = 0; mi < 4; mi++)
#pragma unroll
            for (int ni = 0; ni < 4; ni++) {
                const int col = col0 + wc + ni * 16 + lr;
                const int pi = (col & 127) >> 1;
#pragma unroll
                for (int j = 0; j < 4; j++) {
                    const int row = row0 + wr + mi * 16 + lk * 4 + j;
                    const int tt = row & (TSEQ - 1);
                    const float2 cs = tab[tt * 64 + pi];
                    const float v = acc[mi][ni][j];
                    const float p = __shfl_xor(v, 1, 64);
                    const float o = par ? (p * cs.y + v * cs.x)
                                        : (v * cs.x - p * cs.y);
                    qkvb[(size_t)row * N + col] = f2bf(o);
                }
            }
    } else {
        // v section: transposed packed write to vt[bh][d][token]
#pragma unroll
        for (int mi = 0; mi < 4; mi++) {
            const int rowb = row0 + wr + mi * 16 + lk * 4;
            const int bb = rowb >> 11;
            const int tt = rowb & (TSEQ - 1);
#pragma unroll
            for (int ni = 0; ni < 4; ni++) {
                const int vcol = col0 - 2 * DMODEL + wc + ni * 16 + lr;
                const int h = vcol >> 7, d = vcol & 127;
                uint2 pw;
                pw.x = (uint32_t)f2bf(acc[mi][ni][0]) | ((uint32_t)f2bf(acc[mi][ni][1]) << 16);
                pw.y = (uint32_t)f2bf(acc[mi][ni][2]) | ((uint32_t)f2bf(acc[mi][ni][3]) << 16);
                *(uint2*)&vt[(size_t)((bb * NHEADS + h) * DK + d) * TSEQ + tt] = pw;
            }
        }
    }
}

// ===================== m97-style bf16 GEMM (output projection, f32 out) =====================
template<int OUT_BF16>
__global__ __launch_bounds__(256) void gemm_bt_bf16(
    const unsigned short* __restrict__ A, const unsigned short* __restrict__ B,
    void* __restrict__ Cv, int M, int N, int K)
{
    __shared__ unsigned short As[128 * 32];
    __shared__ unsigned short Bs[128 * 32];

    const int t = threadIdx.x;
    const int lane = t & 63, w = t >> 6;
    const int row0 = blockIdx.y * 128, col0 = blockIdx.x * 128;
    const int wr = (w >> 1) * 64, wc = (w & 1) * 64;
    const int lr = lane & 15, lk = lane >> 4;

    floatx4 acc[4][4];
#pragma unroll
    for (int i = 0; i < 4; i++)
#pragma unroll
        for (int j = 0; j < 4; j++)
#pragma unroll
            for (int e = 0; e < 4; e++) acc[i][j][e] = 0.f;

    const int c0 = w * 64 + lane, c1 = c0 + 256;
    const size_t ga0 = (size_t)(row0 + (c0 >> 2)) * K + ((c0 & 3) << 3);
    const size_t ga1 = (size_t)(row0 + (c1 >> 2)) * K + ((c1 & 3) << 3);
    const size_t gb0 = (size_t)(col0 + (c0 >> 2)) * K + ((c0 & 3) << 3);
    const size_t gb1 = (size_t)(col0 + (c1 >> 2)) * K + ((c1 & 3) << 3);

    for (int k0 = 0; k0 < K; k0 += 32) {
        async16(&As[c0 * 8], A + ga0 + k0);
        async16(&As[c1 * 8], A + ga1 + k0);
        async16(&Bs[c0 * 8], B + gb0 + k0);
        async16(&Bs[c1 * 8], B + gb1 + k0);
        __syncthreads();

        short8 a[4], b[4];
#pragma unroll
        for (int mi = 0; mi < 4; mi++)
            a[mi] = *(const short8*)&As[(wr + mi * 16 + lr) * 32 + lk * 8];
#pragma unroll
        for (int ni = 0; ni < 4; ni++)
            b[ni] = *(const short8*)&Bs[(wc + ni * 16 + lr) * 32 + lk * 8];
#pragma unroll
        for (int mi = 0; mi < 4; mi++)
#pragma unroll
            for (int ni = 0; ni < 4; ni++)
                acc[mi][ni] = __builtin_amdgcn_mfma_f32_16x16x32_bf16(
                    a[mi], b[ni], acc[mi][ni], 0, 0, 0);
        __syncthreads();
    }

#pragma unroll
    for (int mi = 0; mi < 4; mi++)
#pragma unroll
        for (int ni = 0; ni < 4; ni++) {
            const int colb = col0 + wc + ni * 16 + lr;
#pragma unroll
            for (int j = 0; j < 4; j++) {
                const int rowb = row0 + wr + mi * 16 + lk * 4 + j;
                if (OUT_BF16)
                    ((unsigned short*)Cv)[(size_t)rowb * N + colb] = f2bf(acc[mi][ni][j]);
                else
                    ((float*)Cv)[(size_t)rowb * N + colb] = acc[mi][ni][j];
            }
        }
}

// ===================== MFMA flash attention (swapped QK^T, P-swizzled) =====================
__global__ __launch_bounds__(256, 2) void attn_mfma2_kernel(
    const unsigned short* __restrict__ qkvb, const unsigned short* __restrict__ vt,
    unsigned short* __restrict__ outb)
{
    __shared__ unsigned short Ks[2][64 * 128];
    __shared__ unsigned short Vs[128 * 64];
    __shared__ unsigned short Ps[4][32 * 64];

    const int t = threadIdx.x;
    const int lane = t & 63, w = t >> 6;
    const int lr = lane & 15, hi = lane >> 4;
    const int bh = blockIdx.y, b = bh >> 4, h = bh & 15;
    const int qc = (int)gridDim.x - 1 - (int)blockIdx.x;
    const int q0 = qc * 128;
    const int q0w = q0 + w * 32;
    const float scale = 0.08838834764831845f;
    const size_t QROW = 3 * DMODEL;

    const unsigned short* kg = qkvb + (size_t)b * TSEQ * QROW + DMODEL + h * DK;
    const unsigned short* vg = vt + (size_t)bh * DK * TSEQ;

    short8 qf[2][4];
    {
        const unsigned short* qbase = qkvb + (size_t)(b * TSEQ + q0w) * QROW + h * DK;
#pragma unroll
        for (int nt = 0; nt < 2; nt++)
#pragma unroll
            for (int ks = 0; ks < 4; ks++) {
                short8 raw = *(const short8*)(qbase + (size_t)(nt * 16 + lr) * QROW + ks * 32 + hi * 8);
                short8 sc;
#pragma unroll
                for (int e = 0; e < 8; e++)
                    sc[e] = (short)f2bf(bf2f((unsigned short)raw[e]) * scale);
                qf[nt][ks] = sc;
            }
    }

    auto stageK = [&](int bufi, int kv0s) {
#pragma unroll
        for (int i = 0; i < 4; i++) {
            const int s = i * 256 + t;
            const int r = s >> 4;
            const int cc = (s & 15) ^ (r & 7);
            async16(&Ks[bufi][s * 8], kg + (size_t)(kv0s + r) * QROW + cc * 8);
        }
    };
    auto stageV = [&](int kv0s) {
#pragma unroll
        for (int i = 0; i < 4; i++) {
            const int s = i * 256 + t;
            const int r = s >> 3;
            const int cc = (s & 7) ^ (r & 7);
            async16(&Vs[s * 8], vg + (size_t)r * TSEQ + kv0s + cc * 8);
        }
    };

    floatx4 accO[2][8];
#pragma unroll
    for (int nt = 0; nt < 2; nt++)
#pragma unroll
        for (int dt = 0; dt < 8; dt++)
#pragma unroll
            for (int e = 0; e < 4; e++) accO[nt][dt][e] = 0.f;
    float mrun[2] = {-1e30f, -1e30f};
    float lrun[2] = {0.f, 0.f};

    const int ntiles = (q0 + 128) / 64;
    int kbuf = 0;

    stageK(0, 0);
    __syncthreads();

    const int pswz = (lr & 7) << 1;

    for (int ti = 0; ti < ntiles; ti++) {
        const int kv0 = ti * 64;
        stageV(kv0);
        if (ti + 1 < ntiles) stageK(kbuf ^ 1, kv0 + 64);

        const bool active = (kv0 <= q0w + 31);
        float al[2] = {1.f, 1.f};

        if (active) {
            floatx4 st[4][2];
#pragma unroll
            for (int mt = 0; mt < 4; mt++)
#pragma unroll
                for (int nt = 0; nt < 2; nt++)
#pragma unroll
                    for (int e = 0; e < 4; e++) st[mt][nt][e] = 0.f;
#pragma unroll
            for (int mt = 0; mt < 4; mt++) {
                const int r = mt * 16 + lr;
#pragma unroll
                for (int ks = 0; ks < 4; ks++) {
                    const int ch = (ks * 4 + hi) ^ (r & 7);
                    const short8 kf = *(const short8*)&Ks[kbuf][(r * 16 + ch) * 8];
                    st[mt][0] = __builtin_amdgcn_mfma_f32_16x16x32_bf16(kf, qf[0][ks], st[mt][0], 0, 0, 0);
                    st[mt][1] = __builtin_amdgcn_mfma_f32_16x16x32_bf16(kf, qf[1][ks], st[mt][1], 0, 0, 0);
                }
            }
            if (kv0 + 63 > q0w) {
#pragma unroll
                for (int nt = 0; nt < 2; nt++) {
                    const int qg = q0w + nt * 16 + lr;
#pragma unroll
                    for (int mt = 0; mt < 4; mt++)
#pragma unroll
                        for (int rg = 0; rg < 4; rg++) {
                            const int kvg = kv0 + mt * 16 + hi * 4 + rg;
                            if (kvg > qg) st[mt][nt][rg] = -1e30f;
                        }
                }
            }
            float pm[2];
#pragma unroll
            for (int nt = 0; nt < 2; nt++) {
                float m = -1e30f;
#pragma unroll
                for (int mt = 0; mt < 4; mt++)
#pragma unroll
                    for (int rg = 0; rg < 4; rg++) m = fmaxf(m, st[mt][nt][rg]);
                m = fmaxf(m, __shfl_xor(m, 16, 64));
                m = fmaxf(m, __shfl_xor(m, 32, 64));
                pm[nt] = m;
            }
            if (__any((pm[0] > mrun[0] + 8.f) || (pm[1] > mrun[1] + 8.f))) {
#pragma unroll
                for (int nt = 0; nt < 2; nt++) {
                    const float mn = fmaxf(mrun[nt], pm[nt]);
                    al[nt] = __expf(mrun[nt] - mn);
                    mrun[nt] = mn;
                }
#pragma unroll
                for (int rg = 0; rg < 4; rg++) {
                    const float a0 = __shfl(al[0], hi * 4 + rg, 64);
                    const float a1 = __shfl(al[1], hi * 4 + rg, 64);
#pragma unroll
                    for (int dt = 0; dt < 8; dt++) {
                        accO[0][dt][rg] *= a0;
                        accO[1][dt][rg] *= a1;
                    }
                }
            }
            // exp + row-sum + packed swizzled P writes (b64, ~2-way banks)
#pragma unroll
            for (int nt = 0; nt < 2; nt++) {
                float ls = 0.f;
                const int prow = nt * 16 + lr;
#pragma unroll
                for (int mt = 0; mt < 4; mt++) {
                    float pv[4];
#pragma unroll
                    for (int rg = 0; rg < 4; rg++) {
                        pv[rg] = __expf(st[mt][nt][rg] - mrun[nt]);
                        ls += pv[rg];
                    }
                    uint2 pw;
                    pw.x = (uint32_t)f2bf(pv[0]) | ((uint32_t)f2bf(pv[1]) << 16);
                    pw.y = (uint32_t)f2bf(pv[2]) | ((uint32_t)f2bf(pv[3]) << 16);
                    const int chunk = (mt * 4 + hi) ^ pswz;
                    *(uint2*)&Ps[w][prow * 64 + chunk * 4] = pw;
                }
                ls += __shfl_xor(ls, 16, 64);
                ls += __shfl_xor(ls, 32, 64);
                lrun[nt] = lrun[nt] * al[nt] + ls;
            }
        }
        __syncthreads();

        if (active) {
#pragma unroll
            for (int ks2 = 0; ks2 < 2; ks2++) {
                const int ch0 = ((ks2 * 8 + hi * 2) ^ pswz) * 4;
                const short8 pa0 = *(const short8*)&Ps[w][(0 * 16 + lr) * 64 + ch0];
                const short8 pa1 = *(const short8*)&Ps[w][(1 * 16 + lr) * 64 + ch0];
#pragma unroll
                for (int dt = 0; dt < 8; dt++) {
                    const int r = dt * 16 + lr;
                    const int ch = (ks2 * 4 + hi) ^ (r & 7);
                    const short8 vf = *(const short8*)&Vs[(r * 8 + ch) * 8];
                    accO[0][dt] = __builtin_amdgcn_mfma_f32_16x16x32_bf16(pa0, vf, accO[0][dt], 0, 0, 0);
                    accO[1][dt] = __builtin_amdgcn_mfma_f32_16x16x32_bf16(pa1, vf, accO[1][dt], 0, 0, 0);
                }
            }
        }
        __syncthreads();
        kbuf ^= 1;
    }

#pragma unroll
    for (int nt = 0; nt < 2; nt++) {
        const float lv_own = 1.f / lrun[nt];
#pragma unroll
        for (int rg = 0; rg < 4; rg++) {
            const float lv = __shfl(lv_own, hi * 4 + rg, 64);
            unsigned short* orow = outb + (size_t)(b * TSEQ + q0w + nt * 16 + hi * 4 + rg) * DMODEL + h * DK;
#pragma unroll
            for (int dt = 0; dt < 8; dt++)
                orow[dt * 16 + lr] = f2bf(accO[nt][dt][rg] * lv);
        }
    }
}

// ===================== launch =====================
extern "C" void kernel_launch(void* const* d_in, const int* in_sizes, int n_in,
                              void* d_out, int out_size, void* d_ws, size_t ws_size,
                              hipStream_t stream)
{
    const float* x    = (const float*)d_in[0];
    const int*   pos  = (const int*)d_in[1];
    const float* Wqkv = (const float*)d_in[2];
    const float* Wo   = (const float*)d_in[3];
    float* out = (float*)d_out;

    unsigned short* qkvb  = (unsigned short*)d_ws;
    unsigned short* vtb   = qkvb + (size_t)25165824;
    unsigned short* xb    = vtb + (size_t)8388608;
    unsigned short* attnb = xb;                         // alias: xb dead after GEMM1
    unsigned short* wqkvb = xb + (size_t)8388608;
    unsigned short* wob   = wqkvb + (size_t)12582912;
    float2* tab = (float2*)(wob + (size_t)4194304);

    const int M = 2 * TSEQ;   // 4096

    cast_f32_to_bf16<<<4096, 256, 0, stream>>>(x, xb, 1048576);
    cast_f32_to_bf16<<<6144, 256, 0, stream>>>(Wqkv, wqkvb, 1572864);
    cast_f32_to_bf16<<<2048, 256, 0, stream>>>(Wo, wob, 524288);
    rope_table_kernel<<<512, 256, 0, stream>>>(pos, tab);

    // fused QKV projection + RoPE + V-transpose (4096 x 6144 x 2048)
    gemm_qkv_fused<<<dim3(48, 32), 256, 0, stream>>>(xb, wqkvb, qkvb, vtb, tab);

    attn_mfma2_kernel<<<dim3(16, 32), 256, 0, stream>>>(qkvb, vtb, attnb);

    gemm_bt_bf16<0><<<dim3(16, 32), 256, 0, stream>>>(attnb, wob, (void*)out, M, DMODEL, DMODEL);
}

// Round 6
// 298.770 us; speedup vs baseline: 1.2917x; 1.0686x over previous
//
#include <hip/hip_runtime.h>
#include <math.h>
#include <stdint.h>

#define NHEADS 16
#define DK 128
#define TSEQ 2048
#define DMODEL 2048

typedef __attribute__((ext_vector_type(8))) short short8;
typedef __attribute__((ext_vector_type(4))) float floatx4;

__device__ __forceinline__ float bf2f(unsigned short h) {
    return __uint_as_float(((unsigned int)h) << 16);
}
__device__ __forceinline__ unsigned short f2bf(float f) {
    unsigned int u = __float_as_uint(f);
    u += 0x7FFFu + ((u >> 16) & 1u);
    return (unsigned short)(u >> 16);
}
__device__ __forceinline__ void async16(unsigned short* lds, const unsigned short* g) {
    __builtin_amdgcn_global_load_lds(
        (const __attribute__((address_space(1))) uint32_t*)g,
        (__attribute__((address_space(3))) uint32_t*)lds, 16, 0, 0);
}

// ===================== merged cast f32 -> bf16 (x, Wqkv, Wo) =====================
#define NX8 1048576
#define NW8 1572864
#define NO8 524288
__global__ __launch_bounds__(256) void cast_all_bf16(
    const float* __restrict__ x, const float* __restrict__ wqkv, const float* __restrict__ wo,
    unsigned short* __restrict__ xb, unsigned short* __restrict__ wqkvb, unsigned short* __restrict__ wob)
{
    const int i = blockIdx.x * 256 + threadIdx.x;
    const float* src; unsigned short* dst; int k;
    if (i < NX8)            { src = x;    dst = xb;    k = i; }
    else if (i < NX8 + NW8) { src = wqkv; dst = wqkvb; k = i - NX8; }
    else                    { src = wo;   dst = wob;   k = i - NX8 - NW8; }
    const float4* p4 = reinterpret_cast<const float4*>(src) + 2 * (size_t)k;
    const float4 a = p4[0], b = p4[1];
    uint32_t w0 = (uint32_t)f2bf(a.x) | ((uint32_t)f2bf(a.y) << 16);
    uint32_t w1 = (uint32_t)f2bf(a.z) | ((uint32_t)f2bf(a.w) << 16);
    uint32_t w2 = (uint32_t)f2bf(b.x) | ((uint32_t)f2bf(b.y) << 16);
    uint32_t w3 = (uint32_t)f2bf(b.z) | ((uint32_t)f2bf(b.w) << 16);
    uint4 o; o.x = w0; o.y = w1; o.z = w2; o.w = w3;
    *reinterpret_cast<uint4*>(dst + 8 * (size_t)k) = o;
}

// ===================== RoPE table =====================
__global__ __launch_bounds__(256) void rope_table_kernel(
    const int* __restrict__ pos, float2* __restrict__ tab)
{
    const int idx = blockIdx.x * 256 + threadIdx.x;   // 2048*64
    const int tt = idx >> 6, i = idx & 63;
    const double inv_freq = exp(-log(10000.0) * (double)i / 64.0);
    const double ang = (double)pos[tt] * inv_freq;
    tab[idx] = make_float2((float)cos(ang), (float)sin(ang));
}

// ===================== fused QKV GEMM, 8-phase 256x192 =====================
// C = x @ Wqkv^T (4096 x 6144 x 2048). 512 tiles = 2 uniform CU-waves.
// 8 waves (2M x 4N): per-wave 128x48 = 8x3 frags. BK=64, LDS 112KB dbuf.
// Counted vmcnt(7), raw barriers, setprio, chunk-XOR swizzle (both sides).
// Epilogue: q/k cols -> RoPE -> qkvb; v cols -> transposed packed -> vt.
__global__ __launch_bounds__(512, 1) void gemm_qkv_8ph(
    const unsigned short* __restrict__ A, const unsigned short* __restrict__ B,
    unsigned short* __restrict__ qkvb, unsigned short* __restrict__ vt,
    const float2* __restrict__ tab)
{
    const int K = DMODEL, N = 3 * DMODEL;
    __shared__ unsigned short As[2][256 * 64];   // 64 KB
    __shared__ unsigned short Bs[2][192 * 64];   // 48 KB

    const int t = threadIdx.x;
    const int lane = t & 63, w = t >> 6;
    const int wr = w >> 2, wc = w & 3;          // 2M x 4N waves
    const int lr = lane & 15, hi = lane >> 4;

    // XCD col-panel swizzle: xcd = bid&7 owns 4 contiguous 192-col panels.
    const int bid = (int)blockIdx.x;
    const int xcd = bid & 7, local = bid >> 3;   // local in [0,64)
    const int row0 = (local & 15) * 256;
    const int col0 = ((xcd << 2) | (local >> 4)) * 192;

    // staging: A 2048 chunks (rows rr+64i, i=0..3), B 1536 chunks (rows rr+64j, j=0..2);
    // all chunks of thread t share col offset cc (XOR-swizzled source).
    const int rr = t >> 3;
    const int cc = ((t & 7) ^ (rr & 7)) << 3;
    const unsigned short* aP = A + (size_t)(row0 + rr) * K + cc;
    const unsigned short* bP = B + (size_t)(col0 + rr) * K + cc;
    const size_t rstep = (size_t)64 * K;

    floatx4 acc[8][3];
#pragma unroll
    for (int m = 0; m < 8; m++)
#pragma unroll
        for (int n = 0; n < 3; n++)
#pragma unroll
            for (int e = 0; e < 4; e++) acc[m][n][e] = 0.f;

#define STAGE(nb, k0n) do { \
        async16(&As[nb][t * 8],          aP + (k0n)); \
        async16(&As[nb][(t + 512) * 8],  aP + rstep + (k0n)); \
        async16(&As[nb][(t + 1024) * 8], aP + 2 * rstep + (k0n)); \
        async16(&As[nb][(t + 1536) * 8], aP + 3 * rstep + (k0n)); \
        async16(&Bs[nb][t * 8],          bP + (k0n)); \
        async16(&Bs[nb][(t + 512) * 8],  bP + rstep + (k0n)); \
        async16(&Bs[nb][(t + 1024) * 8], bP + 2 * rstep + (k0n)); \
    } while (0)

    STAGE(0, 0);
    const int NT = K >> 6;   // 32
    const int ch0 = (hi ^ (lr & 7)) * 8;         // k-half 0 chunk (elem offset)
    const int ch1 = ((4 + hi) ^ (lr & 7)) * 8;   // k-half 1

    short8 av[4][2], bv[3][2];

    for (int kt = 0; kt < NT; ++kt) {
        const int cur = kt & 1;
        const unsigned short* __restrict__ Ac = &As[cur][0];
        const unsigned short* __restrict__ Bc = &Bs[cur][0];

        // ---- phase 0: prefetch next tile, counted wait, m-half 0 ----
        if (kt + 1 < NT) {
            STAGE(cur ^ 1, (kt + 1) << 6);
            asm volatile("s_waitcnt vmcnt(7)" ::: "memory");
        } else {
            asm volatile("s_waitcnt vmcnt(0)" ::: "memory");
        }
        __builtin_amdgcn_s_barrier();   // tile-kt staging visible to all waves
        __builtin_amdgcn_sched_barrier(0);

#pragma unroll
        for (int m = 0; m < 4; m++) {
            const int ar = (wr * 128 + m * 16 + lr) * 64;
            av[m][0] = *(const short8*)&Ac[ar + ch0];
            av[m][1] = *(const short8*)&Ac[ar + ch1];
        }
#pragma unroll
        for (int n = 0; n < 3; n++) {
            const int br = (wc * 48 + n * 16 + lr) * 64;
            bv[n][0] = *(const short8*)&Bc[br + ch0];
            bv[n][1] = *(const short8*)&Bc[br + ch1];
        }
        asm volatile("s_waitcnt lgkmcnt(0)" ::: "memory");
        __builtin_amdgcn_sched_barrier(0);
        __builtin_amdgcn_s_setprio(1);
#pragma unroll
        for (int m = 0; m < 4; m++)
#pragma unroll
            for (int n = 0; n < 3; n++) {
                acc[m][n] = __builtin_amdgcn_mfma_f32_16x16x32_bf16(av[m][0], bv[n][0], acc[m][n], 0, 0, 0);
                acc[m][n] = __builtin_amdgcn_mfma_f32_16x16x32_bf16(av[m][1], bv[n][1], acc[m][n], 0, 0, 0);
            }
        __builtin_amdgcn_s_setprio(0);
        __builtin_amdgcn_s_barrier();

        // ---- phase 1: m-half 1 (reuse bv) ----
#pragma unroll
        for (int m = 0; m < 4; m++) {
            const int ar = (wr * 128 + 64 + m * 16 + lr) * 64;
            av[m][0] = *(const short8*)&Ac[ar + ch0];
            av[m][1] = *(const short8*)&Ac[ar + ch1];
        }
        __builtin_amdgcn_s_barrier();
        asm volatile("s_waitcnt lgkmcnt(0)" ::: "memory");
        __builtin_amdgcn_sched_barrier(0);
        __builtin_amdgcn_s_setprio(1);
#pragma unroll
        for (int m = 0; m < 4; m++)
#pragma unroll
            for (int n = 0; n < 3; n++) {
                acc[4 + m][n] = __builtin_amdgcn_mfma_f32_16x16x32_bf16(av[m][0], bv[n][0], acc[4 + m][n], 0, 0, 0);
                acc[4 + m][n] = __builtin_amdgcn_mfma_f32_16x16x32_bf16(av[m][1], bv[n][1], acc[4 + m][n], 0, 0, 0);
            }
        __builtin_amdgcn_s_setprio(0);
        __builtin_amdgcn_s_barrier();   // buf[cur] reads done
    }
#undef STAGE

    // ---- fused epilogue (D layout: col=lr, row=hi*4+j) ----
    const int par = lr & 1;
#pragma unroll
    for (int mi = 0; mi < 8; mi++) {
        const int row = row0 + wr * 128 + mi * 16 + hi * 4;
        const int tt = row & (TSEQ - 1);
        const int bb = row >> 11;
#pragma unroll
        for (int ni = 0; ni < 3; ni++) {
            const int col = col0 + wc * 48 + ni * 16 + lr;
            if (col < 2 * DMODEL) {
                // q/k: RoPE in f32 via adjacent-lane exchange
                const int pi = (col & 127) >> 1;
#pragma unroll
                for (int j = 0; j < 4; j++) {
                    const float2 cs = tab[(tt + j) * 64 + pi];
                    const float v = acc[mi][ni][j];
                    const float p = __shfl_xor(v, 1, 64);
                    const float o = par ? (p * cs.y + v * cs.x)
                                        : (v * cs.x - p * cs.y);
                    qkvb[(size_t)(row + j) * N + col] = f2bf(o);
                }
            } else {
                // v: transposed packed write -> vt[bh][d][token]
                const int vcol = col - 2 * DMODEL;
                const int h = vcol >> 7, d = vcol & 127;
                uint2 pw;
                pw.x = (uint32_t)f2bf(acc[mi][ni][0]) | ((uint32_t)f2bf(acc[mi][ni][1]) << 16);
                pw.y = (uint32_t)f2bf(acc[mi][ni][2]) | ((uint32_t)f2bf(acc[mi][ni][3]) << 16);
                *(uint2*)&vt[(size_t)((bb * NHEADS + h) * DK + d) * TSEQ + tt] = pw;
            }
        }
    }
}

// ===================== m97-style bf16 GEMM (output projection, f32 out) =====================
template<int OUT_BF16>
__global__ __launch_bounds__(256) void gemm_bt_bf16(
    const unsigned short* __restrict__ A, const unsigned short* __restrict__ B,
    void* __restrict__ Cv, int M, int N, int K)
{
    __shared__ unsigned short As[128 * 32];
    __shared__ unsigned short Bs[128 * 32];

    const int t = threadIdx.x;
    const int lane = t & 63, w = t >> 6;
    const int row0 = blockIdx.y * 128, col0 = blockIdx.x * 128;
    const int wr = (w >> 1) * 64, wc = (w & 1) * 64;
    const int lr = lane & 15, lk = lane >> 4;

    floatx4 acc[4][4];
#pragma unroll
    for (int i = 0; i < 4; i++)
#pragma unroll
        for (int j = 0; j < 4; j++)
#pragma unroll
            for (int e = 0; e < 4; e++) acc[i][j][e] = 0.f;

    const int c0 = w * 64 + lane, c1 = c0 + 256;
    const size_t ga0 = (size_t)(row0 + (c0 >> 2)) * K + ((c0 & 3) << 3);
    const size_t ga1 = (size_t)(row0 + (c1 >> 2)) * K + ((c1 & 3) << 3);
    const size_t gb0 = (size_t)(col0 + (c0 >> 2)) * K + ((c0 & 3) << 3);
    const size_t gb1 = (size_t)(col0 + (c1 >> 2)) * K + ((c1 & 3) << 3);

    for (int k0 = 0; k0 < K; k0 += 32) {
        async16(&As[c0 * 8], A + ga0 + k0);
        async16(&As[c1 * 8], A + ga1 + k0);
        async16(&Bs[c0 * 8], B + gb0 + k0);
        async16(&Bs[c1 * 8], B + gb1 + k0);
        __syncthreads();

        short8 a[4], b[4];
#pragma unroll
        for (int mi = 0; mi < 4; mi++)
            a[mi] = *(const short8*)&As[(wr + mi * 16 + lr) * 32 + lk * 8];
#pragma unroll
        for (int ni = 0; ni < 4; ni++)
            b[ni] = *(const short8*)&Bs[(wc + ni * 16 + lr) * 32 + lk * 8];
#pragma unroll
        for (int mi = 0; mi < 4; mi++)
#pragma unroll
            for (int ni = 0; ni < 4; ni++)
                acc[mi][ni] = __builtin_amdgcn_mfma_f32_16x16x32_bf16(
                    a[mi], b[ni], acc[mi][ni], 0, 0, 0);
        __syncthreads();
    }

#pragma unroll
    for (int mi = 0; mi < 4; mi++)
#pragma unroll
        for (int ni = 0; ni < 4; ni++) {
            const int colb = col0 + wc + ni * 16 + lr;
#pragma unroll
            for (int j = 0; j < 4; j++) {
                const int rowb = row0 + wr + mi * 16 + lk * 4 + j;
                if (OUT_BF16)
                    ((unsigned short*)Cv)[(size_t)rowb * N + colb] = f2bf(acc[mi][ni][j]);
                else
                    ((float*)Cv)[(size_t)rowb * N + colb] = acc[mi][ni][j];
            }
        }
}

// ===================== MFMA flash attention (swapped QK^T, P-swizzled) =====================
__global__ __launch_bounds__(256, 2) void attn_mfma2_kernel(
    const unsigned short* __restrict__ qkvb, const unsigned short* __restrict__ vt,
    unsigned short* __restrict__ outb)
{
    __shared__ unsigned short Ks[2][64 * 128];
    __shared__ unsigned short Vs[128 * 64];
    __shared__ unsigned short Ps[4][32 * 64];

    const int t = threadIdx.x;
    const int lane = t & 63, w = t >> 6;
    const int lr = lane & 15, hi = lane >> 4;
    const int bh = blockIdx.y, b = bh >> 4, h = bh & 15;
    const int qc = (int)gridDim.x - 1 - (int)blockIdx.x;
    const int q0 = qc * 128;
    const int q0w = q0 + w * 32;
    const float scale = 0.08838834764831845f;
    const size_t QROW = 3 * DMODEL;

    const unsigned short* kg = qkvb + (size_t)b * TSEQ * QROW + DMODEL + h * DK;
    const unsigned short* vg = vt + (size_t)bh * DK * TSEQ;

    short8 qf[2][4];
    {
        const unsigned short* qbase = qkvb + (size_t)(b * TSEQ + q0w) * QROW + h * DK;
#pragma unroll
        for (int nt = 0; nt < 2; nt++)
#pragma unroll
            for (int ks = 0; ks < 4; ks++) {
                short8 raw = *(const short8*)(qbase + (size_t)(nt * 16 + lr) * QROW + ks * 32 + hi * 8);
                short8 sc;
#pragma unroll
                for (int e = 0; e < 8; e++)
                    sc[e] = (short)f2bf(bf2f((unsigned short)raw[e]) * scale);
                qf[nt][ks] = sc;
            }
    }

    auto stageK = [&](int bufi, int kv0s) {
#pragma unroll
        for (int i = 0; i < 4; i++) {
            const int s = i * 256 + t;
            const int r = s >> 4;
            const int cc = (s & 15) ^ (r & 7);
            async16(&Ks[bufi][s * 8], kg + (size_t)(kv0s + r) * QROW + cc * 8);
        }
    };
    auto stageV = [&](int kv0s) {
#pragma unroll
        for (int i = 0; i < 4; i++) {
            const int s = i * 256 + t;
            const int r = s >> 3;
            const int cc = (s & 7) ^ (r & 7);
            async16(&Vs[s * 8], vg + (size_t)r * TSEQ + kv0s + cc * 8);
        }
    };

    floatx4 accO[2][8];
#pragma unroll
    for (int nt = 0; nt < 2; nt++)
#pragma unroll
        for (int dt = 0; dt < 8; dt++)
#pragma unroll
            for (int e = 0; e < 4; e++) accO[nt][dt][e] = 0.f;
    float mrun[2] = {-1e30f, -1e30f};
    float lrun[2] = {0.f, 0.f};

    const int ntiles = (q0 + 128) / 64;
    int kbuf = 0;

    stageK(0, 0);
    __syncthreads();

    const int pswz = (lr & 7) << 1;

    for (int ti = 0; ti < ntiles; ti++) {
        const int kv0 = ti * 64;
        stageV(kv0);
        if (ti + 1 < ntiles) stageK(kbuf ^ 1, kv0 + 64);

        const bool active = (kv0 <= q0w + 31);
        float al[2] = {1.f, 1.f};

        if (active) {
            floatx4 st[4][2];
#pragma unroll
            for (int mt = 0; mt < 4; mt++)
#pragma unroll
                for (int nt = 0; nt < 2; nt++)
#pragma unroll
                    for (int e = 0; e < 4; e++) st[mt][nt][e] = 0.f;
#pragma unroll
            for (int mt = 0; mt < 4; mt++) {
                const int r = mt * 16 + lr;
#pragma unroll
                for (int ks = 0; ks < 4; ks++) {
                    const int ch = (ks * 4 + hi) ^ (r & 7);
                    const short8 kf = *(const short8*)&Ks[kbuf][(r * 16 + ch) * 8];
                    st[mt][0] = __builtin_amdgcn_mfma_f32_16x16x32_bf16(kf, qf[0][ks], st[mt][0], 0, 0, 0);
                    st[mt][1] = __builtin_amdgcn_mfma_f32_16x16x32_bf16(kf, qf[1][ks], st[mt][1], 0, 0, 0);
                }
            }
            if (kv0 + 63 > q0w) {
#pragma unroll
                for (int nt = 0; nt < 2; nt++) {
                    const int qg = q0w + nt * 16 + lr;
#pragma unroll
                    for (int mt = 0; mt < 4; mt++)
#pragma unroll
                        for (int rg = 0; rg < 4; rg++) {
                            const int kvg = kv0 + mt * 16 + hi * 4 + rg;
                            if (kvg > qg) st[mt][nt][rg] = -1e30f;
                        }
                }
            }
            float pm[2];
#pragma unroll
            for (int nt = 0; nt < 2; nt++) {
                float m = -1e30f;
#pragma unroll
                for (int mt = 0; mt < 4; mt++)
#pragma unroll
                    for (int rg = 0; rg < 4; rg++) m = fmaxf(m, st[mt][nt][rg]);
                m = fmaxf(m, __shfl_xor(m, 16, 64));
                m = fmaxf(m, __shfl_xor(m, 32, 64));
                pm[nt] = m;
            }
            if (__any((pm[0] > mrun[0] + 8.f) || (pm[1] > mrun[1] + 8.f))) {
#pragma unroll
                for (int nt = 0; nt < 2; nt++) {
                    const float mn = fmaxf(mrun[nt], pm[nt]);
                    al[nt] = __expf(mrun[nt] - mn);
                    mrun[nt] = mn;
                }
#pragma unroll
                for (int rg = 0; rg < 4; rg++) {
                    const float a0 = __shfl(al[0], hi * 4 + rg, 64);
                    const float a1 = __shfl(al[1], hi * 4 + rg, 64);
#pragma unroll
                    for (int dt = 0; dt < 8; dt++) {
                        accO[0][dt][rg] *= a0;
                        accO[1][dt][rg] *= a1;
                    }
                }
            }
#pragma unroll
            for (int nt = 0; nt < 2; nt++) {
                float ls = 0.f;
                const int prow = nt * 16 + lr;
#pragma unroll
                for (int mt = 0; mt < 4; mt++) {
                    float pv[4];
#pragma unroll
                    for (int rg = 0; rg < 4; rg++) {
                        pv[rg] = __expf(st[mt][nt][rg] - mrun[nt]);
                        ls += pv[rg];
                    }
                    uint2 pw;
                    pw.x = (uint32_t)f2bf(pv[0]) | ((uint32_t)f2bf(pv[1]) << 16);
                    pw.y = (uint32_t)f2bf(pv[2]) | ((uint32_t)f2bf(pv[3]) << 16);
                    const int chunk = (mt * 4 + hi) ^ pswz;
                    *(uint2*)&Ps[w][prow * 64 + chunk * 4] = pw;
                }
                ls += __shfl_xor(ls, 16, 64);
                ls += __shfl_xor(ls, 32, 64);
                lrun[nt] = lrun[nt] * al[nt] + ls;
            }
        }
        __syncthreads();

        if (active) {
#pragma unroll
            for (int ks2 = 0; ks2 < 2; ks2++) {
                const int ch0 = ((ks2 * 8 + hi * 2) ^ pswz) * 4;
                const short8 pa0 = *(const short8*)&Ps[w][(0 * 16 + lr) * 64 + ch0];
                const short8 pa1 = *(const short8*)&Ps[w][(1 * 16 + lr) * 64 + ch0];
#pragma unroll
                for (int dt = 0; dt < 8; dt++) {
                    const int r = dt * 16 + lr;
                    const int ch = (ks2 * 4 + hi) ^ (r & 7);
                    const short8 vf = *(const short8*)&Vs[(r * 8 + ch) * 8];
                    accO[0][dt] = __builtin_amdgcn_mfma_f32_16x16x32_bf16(pa0, vf, accO[0][dt], 0, 0, 0);
                    accO[1][dt] = __builtin_amdgcn_mfma_f32_16x16x32_bf16(pa1, vf, accO[1][dt], 0, 0, 0);
                }
            }
        }
        __syncthreads();
        kbuf ^= 1;
    }

#pragma unroll
    for (int nt = 0; nt < 2; nt++) {
        const float lv_own = 1.f / lrun[nt];
#pragma unroll
        for (int rg = 0; rg < 4; rg++) {
            const float lv = __shfl(lv_own, hi * 4 + rg, 64);
            unsigned short* orow = outb + (size_t)(b * TSEQ + q0w + nt * 16 + hi * 4 + rg) * DMODEL + h * DK;
#pragma unroll
            for (int dt = 0; dt < 8; dt++)
                orow[dt * 16 + lr] = f2bf(accO[nt][dt][rg] * lv);
        }
    }
}

// ===================== launch =====================
extern "C" void kernel_launch(void* const* d_in, const int* in_sizes, int n_in,
                              void* d_out, int out_size, void* d_ws, size_t ws_size,
                              hipStream_t stream)
{
    const float* x    = (const float*)d_in[0];
    const int*   pos  = (const int*)d_in[1];
    const float* Wqkv = (const float*)d_in[2];
    const float* Wo   = (const float*)d_in[3];
    float* out = (float*)d_out;

    unsigned short* qkvb  = (unsigned short*)d_ws;
    unsigned short* vtb   = qkvb + (size_t)25165824;
    unsigned short* xb    = vtb + (size_t)8388608;
    unsigned short* attnb = xb;                         // alias: xb dead after GEMM1
    unsigned short* wqkvb = xb + (size_t)8388608;
    unsigned short* wob   = wqkvb + (size_t)12582912;
    float2* tab = (float2*)(wob + (size_t)4194304);

    const int M = 2 * TSEQ;   // 4096

    cast_all_bf16<<<12288, 256, 0, stream>>>(x, Wqkv, Wo, xb, wqkvb, wob);
    rope_table_kernel<<<512, 256, 0, stream>>>(pos, tab);

    // fused QKV projection + RoPE + V-transpose (4096 x 6144 x 2048), 512 tiles of 256x192
    gemm_qkv_8ph<<<dim3(512), 512, 0, stream>>>(xb, wqkvb, qkvb, vtb, tab);

    attn_mfma2_kernel<<<dim3(16, 32), 256, 0, stream>>>(qkvb, vtb, attnb);

    gemm_bt_bf16<0><<<dim3(16, 32), 256, 0, stream>>>(attnb, wob, (void*)out, M, DMODEL, DMODEL);
}

// Round 7
// 285.770 us; speedup vs baseline: 1.3505x; 1.0455x over previous
//
#include <hip/hip_runtime.h>
#include <math.h>
#include <stdint.h>

#define NHEADS 16
#define DK 128
#define TSEQ 2048
#define DMODEL 2048

typedef __attribute__((ext_vector_type(8))) short short8;
typedef __attribute__((ext_vector_type(4))) float floatx4;

__device__ __forceinline__ float bf2f(unsigned short h) {
    return __uint_as_float(((unsigned int)h) << 16);
}
__device__ __forceinline__ unsigned short f2bf(float f) {
    unsigned int u = __float_as_uint(f);
    u += 0x7FFFu + ((u >> 16) & 1u);
    return (unsigned short)(u >> 16);
}
__device__ __forceinline__ void async16(unsigned short* lds, const unsigned short* g) {
    __builtin_amdgcn_global_load_lds(
        (const __attribute__((address_space(1))) uint32_t*)g,
        (__attribute__((address_space(3))) uint32_t*)lds, 16, 0, 0);
}

// ===================== merged cast f32 -> bf16 (x, Wqkv, Wo) =====================
#define NX8 1048576
#define NW8 1572864
#define NO8 524288
__global__ __launch_bounds__(256) void cast_all_bf16(
    const float* __restrict__ x, const float* __restrict__ wqkv, const float* __restrict__ wo,
    unsigned short* __restrict__ xb, unsigned short* __restrict__ wqkvb, unsigned short* __restrict__ wob)
{
    const int i = blockIdx.x * 256 + threadIdx.x;
    const float* src; unsigned short* dst; int k;
    if (i < NX8)            { src = x;    dst = xb;    k = i; }
    else if (i < NX8 + NW8) { src = wqkv; dst = wqkvb; k = i - NX8; }
    else                    { src = wo;   dst = wob;   k = i - NX8 - NW8; }
    const float4* p4 = reinterpret_cast<const float4*>(src) + 2 * (size_t)k;
    const float4 a = p4[0], b = p4[1];
    uint32_t w0 = (uint32_t)f2bf(a.x) | ((uint32_t)f2bf(a.y) << 16);
    uint32_t w1 = (uint32_t)f2bf(a.z) | ((uint32_t)f2bf(a.w) << 16);
    uint32_t w2 = (uint32_t)f2bf(b.x) | ((uint32_t)f2bf(b.y) << 16);
    uint32_t w3 = (uint32_t)f2bf(b.z) | ((uint32_t)f2bf(b.w) << 16);
    uint4 o; o.x = w0; o.y = w1; o.z = w2; o.w = w3;
    *reinterpret_cast<uint4*>(dst + 8 * (size_t)k) = o;
}

// ===================== RoPE table =====================
__global__ __launch_bounds__(256) void rope_table_kernel(
    const int* __restrict__ pos, float2* __restrict__ tab)
{
    const int idx = blockIdx.x * 256 + threadIdx.x;   // 2048*64
    const int tt = idx >> 6, i = idx & 63;
    const double inv_freq = exp(-log(10000.0) * (double)i / 64.0);
    const double ang = (double)pos[tt] * inv_freq;
    tab[idx] = make_float2((float)cos(ang), (float)sin(ang));
}

// ===================== fused QKV GEMM, 8-phase 256x192 =====================
// C = x @ Wqkv^T (4096 x 6144 x 2048). 512 tiles = 2 uniform CU-waves.
// Split-issue staging: A-prefetch at phase 0, B-prefetch at phase 1, vmcnt(4).
__global__ __launch_bounds__(512, 1) void gemm_qkv_8ph(
    const unsigned short* __restrict__ A, const unsigned short* __restrict__ B,
    unsigned short* __restrict__ qkvb, unsigned short* __restrict__ vt,
    const float2* __restrict__ tab)
{
    const int K = DMODEL, N = 3 * DMODEL;
    __shared__ unsigned short As[2][256 * 64];   // 64 KB
    __shared__ unsigned short Bs[2][192 * 64];   // 48 KB

    const int t = threadIdx.x;
    const int lane = t & 63, w = t >> 6;
    const int wr = w >> 2, wc = w & 3;          // 2M x 4N waves
    const int lr = lane & 15, hi = lane >> 4;

    // XCD col-panel swizzle
    const int bid = (int)blockIdx.x;
    const int xcd = bid & 7, local = bid >> 3;   // local in [0,64)
    const int row0 = (local & 15) * 256;
    const int col0 = ((xcd << 2) | (local >> 4)) * 192;

    const int rr = t >> 3;
    const int cc = ((t & 7) ^ (rr & 7)) << 3;
    const unsigned short* aP = A + (size_t)(row0 + rr) * K + cc;
    const unsigned short* bP = B + (size_t)(col0 + rr) * K + cc;
    const size_t rstep = (size_t)64 * K;

    floatx4 acc[8][3];
#pragma unroll
    for (int m = 0; m < 8; m++)
#pragma unroll
        for (int n = 0; n < 3; n++)
#pragma unroll
            for (int e = 0; e < 4; e++) acc[m][n][e] = 0.f;

#define STAGE_A(nb, k0n) do { \
        async16(&As[nb][t * 8],          aP + (k0n)); \
        async16(&As[nb][(t + 512) * 8],  aP + rstep + (k0n)); \
        async16(&As[nb][(t + 1024) * 8], aP + 2 * rstep + (k0n)); \
        async16(&As[nb][(t + 1536) * 8], aP + 3 * rstep + (k0n)); \
    } while (0)
#define STAGE_B(nb, k0n) do { \
        async16(&Bs[nb][t * 8],          bP + (k0n)); \
        async16(&Bs[nb][(t + 512) * 8],  bP + rstep + (k0n)); \
        async16(&Bs[nb][(t + 1024) * 8], bP + 2 * rstep + (k0n)); \
    } while (0)

    STAGE_A(0, 0);
    STAGE_B(0, 0);
    const int NT = K >> 6;   // 32
    const int ch0 = (hi ^ (lr & 7)) * 8;
    const int ch1 = ((4 + hi) ^ (lr & 7)) * 8;

    short8 av[4][2], bv[3][2];

    for (int kt = 0; kt < NT; ++kt) {
        const int cur = kt & 1;
        const unsigned short* __restrict__ Ac = &As[cur][0];
        const unsigned short* __restrict__ Bc = &Bs[cur][0];

        // ---- phase 0: A-prefetch, counted wait, m-half 0 ----
        if (kt + 1 < NT) {
            STAGE_A(cur ^ 1, (kt + 1) << 6);
            asm volatile("s_waitcnt vmcnt(4)" ::: "memory");
        } else {
            asm volatile("s_waitcnt vmcnt(0)" ::: "memory");
        }
        __builtin_amdgcn_s_barrier();
        __builtin_amdgcn_sched_barrier(0);

#pragma unroll
        for (int m = 0; m < 4; m++) {
            const int ar = (wr * 128 + m * 16 + lr) * 64;
            av[m][0] = *(const short8*)&Ac[ar + ch0];
            av[m][1] = *(const short8*)&Ac[ar + ch1];
        }
#pragma unroll
        for (int n = 0; n < 3; n++) {
            const int br = (wc * 48 + n * 16 + lr) * 64;
            bv[n][0] = *(const short8*)&Bc[br + ch0];
            bv[n][1] = *(const short8*)&Bc[br + ch1];
        }
        asm volatile("s_waitcnt lgkmcnt(0)" ::: "memory");
        __builtin_amdgcn_sched_barrier(0);
        __builtin_amdgcn_s_setprio(1);
#pragma unroll
        for (int m = 0; m < 4; m++)
#pragma unroll
            for (int n = 0; n < 3; n++) {
                acc[m][n] = __builtin_amdgcn_mfma_f32_16x16x32_bf16(av[m][0], bv[n][0], acc[m][n], 0, 0, 0);
                acc[m][n] = __builtin_amdgcn_mfma_f32_16x16x32_bf16(av[m][1], bv[n][1], acc[m][n], 0, 0, 0);
            }
        __builtin_amdgcn_s_setprio(0);
        __builtin_amdgcn_s_barrier();

        // ---- phase 1: B-prefetch, m-half 1 (reuse bv) ----
        if (kt + 1 < NT) STAGE_B(cur ^ 1, (kt + 1) << 6);
#pragma unroll
        for (int m = 0; m < 4; m++) {
            const int ar = (wr * 128 + 64 + m * 16 + lr) * 64;
            av[m][0] = *(const short8*)&Ac[ar + ch0];
            av[m][1] = *(const short8*)&Ac[ar + ch1];
        }
        __builtin_amdgcn_s_barrier();
        asm volatile("s_waitcnt lgkmcnt(0)" ::: "memory");
        __builtin_amdgcn_sched_barrier(0);
        __builtin_amdgcn_s_setprio(1);
#pragma unroll
        for (int m = 0; m < 4; m++)
#pragma unroll
            for (int n = 0; n < 3; n++) {
                acc[4 + m][n] = __builtin_amdgcn_mfma_f32_16x16x32_bf16(av[m][0], bv[n][0], acc[4 + m][n], 0, 0, 0);
                acc[4 + m][n] = __builtin_amdgcn_mfma_f32_16x16x32_bf16(av[m][1], bv[n][1], acc[4 + m][n], 0, 0, 0);
            }
        __builtin_amdgcn_s_setprio(0);
        __builtin_amdgcn_s_barrier();
    }
#undef STAGE_A
#undef STAGE_B

    // ---- fused epilogue (D layout: col=lr, row=hi*4+j) ----
    const int par = lr & 1;
#pragma unroll
    for (int mi = 0; mi < 8; mi++) {
        const int row = row0 + wr * 128 + mi * 16 + hi * 4;
        const int tt = row & (TSEQ - 1);
        const int bb = row >> 11;
#pragma unroll
        for (int ni = 0; ni < 3; ni++) {
            const int col = col0 + wc * 48 + ni * 16 + lr;
            if (col < 2 * DMODEL) {
                const int pi = (col & 127) >> 1;
#pragma unroll
                for (int j = 0; j < 4; j++) {
                    const float2 cs = tab[(tt + j) * 64 + pi];
                    const float v = acc[mi][ni][j];
                    const float p = __shfl_xor(v, 1, 64);
                    const float o = par ? (p * cs.y + v * cs.x)
                                        : (v * cs.x - p * cs.y);
                    qkvb[(size_t)(row + j) * N + col] = f2bf(o);
                }
            } else {
                const int vcol = col - 2 * DMODEL;
                const int h = vcol >> 7, d = vcol & 127;
                uint2 pw;
                pw.x = (uint32_t)f2bf(acc[mi][ni][0]) | ((uint32_t)f2bf(acc[mi][ni][1]) << 16);
                pw.y = (uint32_t)f2bf(acc[mi][ni][2]) | ((uint32_t)f2bf(acc[mi][ni][3]) << 16);
                *(uint2*)&vt[(size_t)((bb * NHEADS + h) * DK + d) * TSEQ + tt] = pw;
            }
        }
    }
}

// ===================== output projection, 8-phase 256x128, f32 out =====================
// C = attn @ Wo^T (4096 x 2048 x 2048). Grid 256 = exactly 1 CU-wave.
__global__ __launch_bounds__(512, 1) void gemm_o_8ph(
    const unsigned short* __restrict__ A, const unsigned short* __restrict__ B,
    float* __restrict__ C)
{
    const int K = DMODEL, N = DMODEL;
    __shared__ unsigned short As[2][256 * 64];   // 64 KB
    __shared__ unsigned short Bs[2][128 * 64];   // 32 KB

    const int t = threadIdx.x;
    const int lane = t & 63, w = t >> 6;
    const int wr = w >> 2, wc = w & 3;
    const int lr = lane & 15, hi = lane >> 4;

    const int bid = (int)blockIdx.x;
    const int xcd = bid & 7, local = bid >> 3;   // local in [0,32)
    const int row0 = (local & 15) * 256;
    const int col0 = ((xcd << 1) | (local >> 4)) * 128;

    const int rr = t >> 3;
    const int cc = ((t & 7) ^ (rr & 7)) << 3;
    const unsigned short* aP = A + (size_t)(row0 + rr) * K + cc;
    const unsigned short* bP = B + (size_t)(col0 + rr) * K + cc;
    const size_t rstep = (size_t)64 * K;

    floatx4 acc[8][2];
#pragma unroll
    for (int m = 0; m < 8; m++)
#pragma unroll
        for (int n = 0; n < 2; n++)
#pragma unroll
            for (int e = 0; e < 4; e++) acc[m][n][e] = 0.f;

#define STAGE(nb, k0n) do { \
        async16(&As[nb][t * 8],          aP + (k0n)); \
        async16(&As[nb][(t + 512) * 8],  aP + rstep + (k0n)); \
        async16(&As[nb][(t + 1024) * 8], aP + 2 * rstep + (k0n)); \
        async16(&As[nb][(t + 1536) * 8], aP + 3 * rstep + (k0n)); \
        async16(&Bs[nb][t * 8],          bP + (k0n)); \
        async16(&Bs[nb][(t + 512) * 8],  bP + rstep + (k0n)); \
    } while (0)

    STAGE(0, 0);
    const int NT = K >> 6;   // 32
    const int ch0 = (hi ^ (lr & 7)) * 8;
    const int ch1 = ((4 + hi) ^ (lr & 7)) * 8;

    short8 av[4][2], bv[2][2];

    for (int kt = 0; kt < NT; ++kt) {
        const int cur = kt & 1;
        const unsigned short* __restrict__ Ac = &As[cur][0];
        const unsigned short* __restrict__ Bc = &Bs[cur][0];

        // ---- phase 0: prefetch, counted wait, m-half 0 ----
        if (kt + 1 < NT) {
            STAGE(cur ^ 1, (kt + 1) << 6);
            asm volatile("s_waitcnt vmcnt(6)" ::: "memory");
        } else {
            asm volatile("s_waitcnt vmcnt(0)" ::: "memory");
        }
        __builtin_amdgcn_s_barrier();
        __builtin_amdgcn_sched_barrier(0);

#pragma unroll
        for (int m = 0; m < 4; m++) {
            const int ar = (wr * 128 + m * 16 + lr) * 64;
            av[m][0] = *(const short8*)&Ac[ar + ch0];
            av[m][1] = *(const short8*)&Ac[ar + ch1];
        }
#pragma unroll
        for (int n = 0; n < 2; n++) {
            const int br = (wc * 32 + n * 16 + lr) * 64;
            bv[n][0] = *(const short8*)&Bc[br + ch0];
            bv[n][1] = *(const short8*)&Bc[br + ch1];
        }
        asm volatile("s_waitcnt lgkmcnt(0)" ::: "memory");
        __builtin_amdgcn_sched_barrier(0);
        __builtin_amdgcn_s_setprio(1);
#pragma unroll
        for (int m = 0; m < 4; m++)
#pragma unroll
            for (int n = 0; n < 2; n++) {
                acc[m][n] = __builtin_amdgcn_mfma_f32_16x16x32_bf16(av[m][0], bv[n][0], acc[m][n], 0, 0, 0);
                acc[m][n] = __builtin_amdgcn_mfma_f32_16x16x32_bf16(av[m][1], bv[n][1], acc[m][n], 0, 0, 0);
            }
        __builtin_amdgcn_s_setprio(0);
        __builtin_amdgcn_s_barrier();

        // ---- phase 1: m-half 1 (reuse bv) ----
#pragma unroll
        for (int m = 0; m < 4; m++) {
            const int ar = (wr * 128 + 64 + m * 16 + lr) * 64;
            av[m][0] = *(const short8*)&Ac[ar + ch0];
            av[m][1] = *(const short8*)&Ac[ar + ch1];
        }
        __builtin_amdgcn_s_barrier();
        asm volatile("s_waitcnt lgkmcnt(0)" ::: "memory");
        __builtin_amdgcn_sched_barrier(0);
        __builtin_amdgcn_s_setprio(1);
#pragma unroll
        for (int m = 0; m < 4; m++)
#pragma unroll
            for (int n = 0; n < 2; n++) {
                acc[4 + m][n] = __builtin_amdgcn_mfma_f32_16x16x32_bf16(av[m][0], bv[n][0], acc[4 + m][n], 0, 0, 0);
                acc[4 + m][n] = __builtin_amdgcn_mfma_f32_16x16x32_bf16(av[m][1], bv[n][1], acc[4 + m][n], 0, 0, 0);
            }
        __builtin_amdgcn_s_setprio(0);
        __builtin_amdgcn_s_barrier();
    }
#undef STAGE

    // ---- epilogue: f32 write (D layout: col=lr, row=hi*4+j) ----
#pragma unroll
    for (int mi = 0; mi < 8; mi++) {
        const int row = row0 + wr * 128 + mi * 16 + hi * 4;
#pragma unroll
        for (int ni = 0; ni < 2; ni++) {
            const int col = col0 + wc * 32 + ni * 16 + lr;
#pragma unroll
            for (int j = 0; j < 4; j++)
                C[(size_t)(row + j) * N + col] = acc[mi][ni][j];
        }
    }
}

// ===================== MFMA flash attention (counted-vmcnt barriers) =====================
__global__ __launch_bounds__(256, 2) void attn_mfma2_kernel(
    const unsigned short* __restrict__ qkvb, const unsigned short* __restrict__ vt,
    unsigned short* __restrict__ outb)
{
    __shared__ unsigned short Ks[2][64 * 128];
    __shared__ unsigned short Vs[128 * 64];
    __shared__ unsigned short Ps[4][32 * 64];

    const int t = threadIdx.x;
    const int lane = t & 63, w = t >> 6;
    const int lr = lane & 15, hi = lane >> 4;
    const int bh = blockIdx.y, b = bh >> 4, h = bh & 15;
    const int qc = (int)gridDim.x - 1 - (int)blockIdx.x;
    const int q0 = qc * 128;
    const int q0w = q0 + w * 32;
    const float scale = 0.08838834764831845f;
    const size_t QROW = 3 * DMODEL;

    const unsigned short* kg = qkvb + (size_t)b * TSEQ * QROW + DMODEL + h * DK;
    const unsigned short* vg = vt + (size_t)bh * DK * TSEQ;

    short8 qf[2][4];
    {
        const unsigned short* qbase = qkvb + (size_t)(b * TSEQ + q0w) * QROW + h * DK;
#pragma unroll
        for (int nt = 0; nt < 2; nt++)
#pragma unroll
            for (int ks = 0; ks < 4; ks++) {
                short8 raw = *(const short8*)(qbase + (size_t)(nt * 16 + lr) * QROW + ks * 32 + hi * 8);
                short8 sc;
#pragma unroll
                for (int e = 0; e < 8; e++)
                    sc[e] = (short)f2bf(bf2f((unsigned short)raw[e]) * scale);
                qf[nt][ks] = sc;
            }
    }

    auto stageK = [&](int bufi, int kv0s) {
#pragma unroll
        for (int i = 0; i < 4; i++) {
            const int s = i * 256 + t;
            const int r = s >> 4;
            const int cc = (s & 15) ^ (r & 7);
            async16(&Ks[bufi][s * 8], kg + (size_t)(kv0s + r) * QROW + cc * 8);
        }
    };
    auto stageV = [&](int kv0s) {
#pragma unroll
        for (int i = 0; i < 4; i++) {
            const int s = i * 256 + t;
            const int r = s >> 3;
            const int cc = (s & 7) ^ (r & 7);
            async16(&Vs[s * 8], vg + (size_t)r * TSEQ + kv0s + cc * 8);
        }
    };

    floatx4 accO[2][8];
#pragma unroll
    for (int nt = 0; nt < 2; nt++)
#pragma unroll
        for (int dt = 0; dt < 8; dt++)
#pragma unroll
            for (int e = 0; e < 4; e++) accO[nt][dt][e] = 0.f;
    float mrun[2] = {-1e30f, -1e30f};
    float lrun[2] = {0.f, 0.f};

    const int ntiles = (q0 + 128) / 64;
    int kbuf = 0;

    stageK(0, 0);
    __syncthreads();

    const int pswz = (lr & 7) << 1;

    for (int ti = 0; ti < ntiles; ti++) {
        const int kv0 = ti * 64;
        const bool havK = (ti + 1 < ntiles);
        stageV(kv0);
        if (havK) stageK(kbuf ^ 1, kv0 + 64);

        const bool active = (kv0 <= q0w + 31);
        float al[2] = {1.f, 1.f};

        if (active) {
            floatx4 st[4][2];
#pragma unroll
            for (int mt = 0; mt < 4; mt++)
#pragma unroll
                for (int nt = 0; nt < 2; nt++)
#pragma unroll
                    for (int e = 0; e < 4; e++) st[mt][nt][e] = 0.f;
#pragma unroll
            for (int mt = 0; mt < 4; mt++) {
                const int r = mt * 16 + lr;
#pragma unroll
                for (int ks = 0; ks < 4; ks++) {
                    const int ch = (ks * 4 + hi) ^ (r & 7);
                    const short8 kf = *(const short8*)&Ks[kbuf][(r * 16 + ch) * 8];
                    st[mt][0] = __builtin_amdgcn_mfma_f32_16x16x32_bf16(kf, qf[0][ks], st[mt][0], 0, 0, 0);
                    st[mt][1] = __builtin_amdgcn_mfma_f32_16x16x32_bf16(kf, qf[1][ks], st[mt][1], 0, 0, 0);
                }
            }
            if (kv0 + 63 > q0w) {
#pragma unroll
                for (int nt = 0; nt < 2; nt++) {
                    const int qg = q0w + nt * 16 + lr;
#pragma unroll
                    for (int mt = 0; mt < 4; mt++)
#pragma unroll
                        for (int rg = 0; rg < 4; rg++) {
                            const int kvg = kv0 + mt * 16 + hi * 4 + rg;
                            if (kvg > qg) st[mt][nt][rg] = -1e30f;
                        }
                }
            }
            float pm[2];
#pragma unroll
            for (int nt = 0; nt < 2; nt++) {
                float m = -1e30f;
#pragma unroll
                for (int mt = 0; mt < 4; mt++)
#pragma unroll
                    for (int rg = 0; rg < 4; rg++) m = fmaxf(m, st[mt][nt][rg]);
                m = fmaxf(m, __shfl_xor(m, 16, 64));
                m = fmaxf(m, __shfl_xor(m, 32, 64));
                pm[nt] = m;
            }
            if (__any((pm[0] > mrun[0] + 8.f) || (pm[1] > mrun[1] + 8.f))) {
#pragma unroll
                for (int nt = 0; nt < 2; nt++) {
                    const float mn = fmaxf(mrun[nt], pm[nt]);
                    al[nt] = __expf(mrun[nt] - mn);
                    mrun[nt] = mn;
                }
#pragma unroll
                for (int rg = 0; rg < 4; rg++) {
                    const float a0 = __shfl(al[0], hi * 4 + rg, 64);
                    const float a1 = __shfl(al[1], hi * 4 + rg, 64);
#pragma unroll
                    for (int dt = 0; dt < 8; dt++) {
                        accO[0][dt][rg] *= a0;
                        accO[1][dt][rg] *= a1;
                    }
                }
            }
#pragma unroll
            for (int nt = 0; nt < 2; nt++) {
                float ls = 0.f;
                const int prow = nt * 16 + lr;
#pragma unroll
                for (int mt = 0; mt < 4; mt++) {
                    float pv[4];
#pragma unroll
                    for (int rg = 0; rg < 4; rg++) {
                        pv[rg] = __expf(st[mt][nt][rg] - mrun[nt]);
                        ls += pv[rg];
                    }
                    uint2 pw;
                    pw.x = (uint32_t)f2bf(pv[0]) | ((uint32_t)f2bf(pv[1]) << 16);
                    pw.y = (uint32_t)f2bf(pv[2]) | ((uint32_t)f2bf(pv[3]) << 16);
                    const int chunk = (mt * 4 + hi) ^ pswz;
                    *(uint2*)&Ps[w][prow * 64 + chunk * 4] = pw;
                }
                ls += __shfl_xor(ls, 16, 64);
                ls += __shfl_xor(ls, 32, 64);
                lrun[nt] = lrun[nt] * al[nt] + ls;
            }
        }
        // mid barrier: V must be landed; next-tile K may stay in flight
        if (havK) asm volatile("s_waitcnt vmcnt(4)" ::: "memory");
        else      asm volatile("s_waitcnt vmcnt(0)" ::: "memory");
        __builtin_amdgcn_s_barrier();

        if (active) {
#pragma unroll
            for (int ks2 = 0; ks2 < 2; ks2++) {
                const int ch0 = ((ks2 * 8 + hi * 2) ^ pswz) * 4;
                const short8 pa0 = *(const short8*)&Ps[w][(0 * 16 + lr) * 64 + ch0];
                const short8 pa1 = *(const short8*)&Ps[w][(1 * 16 + lr) * 64 + ch0];
#pragma unroll
                for (int dt = 0; dt < 8; dt++) {
                    const int r = dt * 16 + lr;
                    const int ch = (ks2 * 4 + hi) ^ (r & 7);
                    const short8 vf = *(const short8*)&Vs[(r * 8 + ch) * 8];
                    accO[0][dt] = __builtin_amdgcn_mfma_f32_16x16x32_bf16(pa0, vf, accO[0][dt], 0, 0, 0);
                    accO[1][dt] = __builtin_amdgcn_mfma_f32_16x16x32_bf16(pa1, vf, accO[1][dt], 0, 0, 0);
                }
            }
        }
        // end barrier: next-tile K landed; all waves done reading Vs
        asm volatile("s_waitcnt vmcnt(0)" ::: "memory");
        __builtin_amdgcn_s_barrier();
        kbuf ^= 1;
    }

#pragma unroll
    for (int nt = 0; nt < 2; nt++) {
        const float lv_own = 1.f / lrun[nt];
#pragma unroll
        for (int rg = 0; rg < 4; rg++) {
            const float lv = __shfl(lv_own, hi * 4 + rg, 64);
            unsigned short* orow = outb + (size_t)(b * TSEQ + q0w + nt * 16 + hi * 4 + rg) * DMODEL + h * DK;
#pragma unroll
            for (int dt = 0; dt < 8; dt++)
                orow[dt * 16 + lr] = f2bf(accO[nt][dt][rg] * lv);
        }
    }
}

// ===================== launch =====================
extern "C" void kernel_launch(void* const* d_in, const int* in_sizes, int n_in,
                              void* d_out, int out_size, void* d_ws, size_t ws_size,
                              hipStream_t stream)
{
    const float* x    = (const float*)d_in[0];
    const int*   pos  = (const int*)d_in[1];
    const float* Wqkv = (const float*)d_in[2];
    const float* Wo   = (const float*)d_in[3];
    float* out = (float*)d_out;

    unsigned short* qkvb  = (unsigned short*)d_ws;
    unsigned short* vtb   = qkvb + (size_t)25165824;
    unsigned short* xb    = vtb + (size_t)8388608;
    unsigned short* attnb = xb;                         // alias: xb dead after GEMM1
    unsigned short* wqkvb = xb + (size_t)8388608;
    unsigned short* wob   = wqkvb + (size_t)12582912;
    float2* tab = (float2*)(wob + (size_t)4194304);

    cast_all_bf16<<<12288, 256, 0, stream>>>(x, Wqkv, Wo, xb, wqkvb, wob);
    rope_table_kernel<<<512, 256, 0, stream>>>(pos, tab);

    // fused QKV projection + RoPE + V-transpose (4096 x 6144 x 2048)
    gemm_qkv_8ph<<<dim3(512), 512, 0, stream>>>(xb, wqkvb, qkvb, vtb, tab);

    attn_mfma2_kernel<<<dim3(16, 32), 256, 0, stream>>>(qkvb, vtb, attnb);

    // out = attn @ Wo^T (4096 x 2048 x 2048), 8-phase, grid 256 = 1 CU-wave
    gemm_o_8ph<<<dim3(256), 512, 0, stream>>>(attnb, wob, out);
}